// Round 5
// baseline (698.340 us; speedup 1.0000x reference)
//
#include <hip/hip_runtime.h>
#include <math.h>

typedef unsigned short u16;
typedef __attribute__((ext_vector_type(8))) short frag_ab;  // 8 bf16
typedef __attribute__((ext_vector_type(4))) float frag_cd;  // 4 fp32

#define BATCH 8
#define NN 128
#define FS 128
#define FV 64
#define NB 8
#define HID 64
#define ROUT 320
#define HSTRB 72    // hid bf16 LDS row stride (shorts)

// ---- ws layout (float offsets); s:[b][f][n], V:[b][f*3+c3][n], t:[b][g][n] ----
#define SZ_S (BATCH*FS*NN)
#define SZ_V (BATCH*FV*3*NN)
#define SZ_T (BATCH*FV*NN)
#define N_W2B (2*ROUT*HID)          // ushort count
#define OFF_SA 0
#define OFF_SB (OFF_SA+SZ_S)
#define OFF_VA (OFF_SB+SZ_S)
#define OFF_VB (OFF_VA+SZ_V)
#define OFF_T0 (OFF_VB+SZ_V)
#define OFF_T1 (OFF_T0+SZ_T)
#define OFF_COM (OFF_T1+SZ_T)       // 24 floats
#define OFF_W2B (OFF_COM+24)        // N_W2B ushorts

__device__ __forceinline__ float silu_f(float x){ return x * (1.0f/(1.0f + __expf(-x))); }

__device__ __forceinline__ u16 f2bf(float x){
  union { float f; unsigned int u; } v; v.f = x;
  unsigned int r = v.u + 0x7fffu + ((v.u >> 16) & 1u);
  return (u16)(r >> 16);
}

__global__ void init_kernel(const float* __restrict__ x, const float* __restrict__ species,
                            const float* __restrict__ Wr2, const float* __restrict__ Wsv0,
                            float* __restrict__ ws)
{
  int idx = blockIdx.x*blockDim.x + threadIdx.x;
  const int total = SZ_S + SZ_V + SZ_T + N_W2B + 24;
  for (; idx < total; idx += gridDim.x*blockDim.x) {
    int t = idx;
    if (t < SZ_S) { int f = (t>>7)&127; ws[OFF_SA+t] = species[f]; continue; }
    t -= SZ_S;
    if (t < SZ_V) { ws[OFF_VA+t] = 0.f; continue; }
    t -= SZ_V;
    if (t < SZ_T) {
      int g = (t>>7)&63;
      float a = 0.f;
      for (int f=0; f<FS; f++) a = fmaf(species[f], Wsv0[f*FV+g], a);
      ws[OFF_T0+t] = a; continue;
    }
    t -= SZ_T;
    if (t < N_W2B) {
      // w2b[(l*320+c)*64 + j] = bf16(Wr2[l][j][c])
      int j = t & 63; int c = (t>>6)%ROUT; int l = t/(ROUT*HID);
      ((u16*)(ws+OFF_W2B))[t] = f2bf(Wr2[l*HID*ROUT + j*ROUT + c]); continue;
    }
    t -= N_W2B;
    { int bb=t/3, c3=t-bb*3;
      float a=0.f;
      for(int n=0;n<NN;n++) a += x[(bb*NN+n)*3+c3];
      ws[OFF_COM+t] = a*(1.0f/128.0f); }
  }
}

// one block per (batch, receiver k); 512 threads = 8 waves.
// wave w: wq=w&3 channel group (tiles ntg=q*4+wq), sh=w>>2 sender half.
__global__ __launch_bounds__(512, 8) void layer_kernel(
    const float* __restrict__ pos,
    const float* __restrict__ sIn,    // [b][f][n]
    const float* __restrict__ vIn,    // [b][f*3+c3][n]
    const float* __restrict__ tIn,    // [b][g][n]
    float* __restrict__ sOut,         // null if doOut
    float* __restrict__ vOut,
    float* __restrict__ tOut,         // may be null
    const float* __restrict__ Wr1l,   // (8,64)
    const u16*   __restrict__ w2bl,   // (320,64) bf16, c-major
    const float* __restrict__ WmixSl, // (192,128)
    const float* __restrict__ WmixVl, // (128,64)
    const float* __restrict__ WsvNext,// (128,64) or null
    const float* __restrict__ WoutS,  // non-null => fused output epilogue
    const float* __restrict__ WoutV,
    const float* __restrict__ comv,
    float* __restrict__ outp)
{
  const int tid  = threadIdx.x;
  const int b    = blockIdx.x >> 7;
  const int k    = blockIdx.x & 127;
  const int w    = tid >> 6;
  const int lane = tid & 63;
  const int col  = lane & 15;
  const int quad = lane >> 4;
  const int wq   = w & 3;       // channel group
  const int sh   = w >> 2;      // sender half

  __shared__ u16   hidB[128*HSTRB];           // 18.4 KB
  __shared__ float vhx[128], vhy[128], vhz[128];
  __shared__ float aggP[2][576];              // [senderhalf][S(192) V1(192) V2(192)]
  __shared__ float aggC[576];
  __shared__ float sNew[FS];
  __shared__ float vNewL[192];

  const float* pb = pos + b*NN*3;

  // ---- phase 0: threads 0..255, thread t computes half a hid row for sender i=t&127 ----
  if (tid < 256){
    const int i    = tid & 127;
    const int half = tid >> 7;
    float vx = pb[k*3+0]-pb[i*3+0];
    float vy = pb[k*3+1]-pb[i*3+1];
    float vz = pb[k*3+2]-pb[i*3+2];
    float r = sqrtf(vx*vx+vy*vy+vz*vz) + 1e-8f;
    float inv = 1.0f/r;
    if (half==0){ vhx[i]=vx*inv; vhy[i]=vy*inv; vhz[i]=vz*inv; }
    float u = r*0.2f;
    float env = 0.0f;
    if (u < 1.0f && i != k){
      float u2=u*u, u6=u2*u2*u2;
      env = 1.0f - 28.0f*u6 + 48.0f*u6*u - 21.0f*u6*u2;
    }
    float coef = 0.6324555320336759f * inv * env;  // 0 for self / out-of-range
    float arg  = r * 0.6283185307179586f;
    float rb[NB];
    #pragma unroll
    for(int n=0;n<NB;n++) rb[n] = coef * __sinf(arg*(float)(n+1));
    u16* hrow = hidB + i*HSTRB;
    #pragma unroll
    for(int jg=0;jg<8;jg++){
      const int jgg = half*8 + jg;
      float h0=0.f,h1=0.f,h2=0.f,h3=0.f;
      #pragma unroll
      for(int n=0;n<NB;n++){
        const float* wr = Wr1l + n*HID + jgg*4;
        float rn = rb[n];
        h0 = fmaf(rn, wr[0], h0);
        h1 = fmaf(rn, wr[1], h1);
        h2 = fmaf(rn, wr[2], h2);
        h3 = fmaf(rn, wr[3], h3);
      }
      ushort4 uu = make_ushort4(f2bf(silu_f(h0)), f2bf(silu_f(h1)),
                                f2bf(silu_f(h2)), f2bf(silu_f(h3)));
      *(ushort4*)(hrow + jgg*4) = uu;
    }
  }

  // ---- B fragments: 5 interleaved N-tiles x 2 K-halves (global, L2-resident) ----
  frag_ab bfr[5][2];
  #pragma unroll
  for (int q=0;q<5;q++){
    const int c = (q*4+wq)*16 + col;
    const u16* wp = w2bl + c*HID + quad*8;
    bfr[q][0] = *(const frag_ab*)(wp);
    bfr[q][1] = *(const frag_ab*)(wp + 32);
  }

  __syncthreads();

  const float* sIb = sIn + b*FS*NN;
  const float* vIb = vIn + b*FV*3*NN;
  const float* tIb = tIn + b*FV*NN;

  float pA[5] = {0.f,0.f,0.f,0.f,0.f};
  float pX[5] = {0.f,0.f,0.f,0.f,0.f};
  float pY[5] = {0.f,0.f,0.f,0.f,0.f};
  float pZ[5] = {0.f,0.f,0.f,0.f,0.f};

  #pragma unroll
  for (int mt=0; mt<4; mt++){
    const int gi  = sh*64 + mt*16;       // sender tile base (global)
    const int i0  = gi + quad*4;
    const frag_ab a0 = *(const frag_ab*)&hidB[(gi+col)*HSTRB + quad*8];
    const frag_ab a1 = *(const frag_ab*)&hidB[(gi+col)*HSTRB + 32 + quad*8];
    const float4 hx4 = *(const float4*)&vhx[i0];
    const float4 hy4 = *(const float4*)&vhy[i0];
    const float4 hz4 = *(const float4*)&vhz[i0];
    #pragma unroll
    for (int q=0;q<5;q++){
      frag_cd acc = {0.f,0.f,0.f,0.f};
      acc = __builtin_amdgcn_mfma_f32_16x16x32_bf16(a0, bfr[q][0], acc, 0,0,0);
      acc = __builtin_amdgcn_mfma_f32_16x16x32_bf16(a1, bfr[q][1], acc, 0,0,0);
      const int ntg = q*4+wq;
      const int c = ntg*16 + col;
      if (ntg < 8){
        float4 s4 = *(const float4*)&sIb[c*NN + i0];
        pA[q] += acc[0]*s4.x + acc[1]*s4.y + acc[2]*s4.z + acc[3]*s4.w;
      } else if (ntg < 12){
        const int f = c - FS;
        float4 vx4 = *(const float4*)&vIb[(f*3+0)*NN + i0];
        float4 vy4 = *(const float4*)&vIb[(f*3+1)*NN + i0];
        float4 vz4 = *(const float4*)&vIb[(f*3+2)*NN + i0];
        float d0 = vx4.x*hx4.x + vy4.x*hy4.x + vz4.x*hz4.x;
        float d1 = vx4.y*hx4.y + vy4.y*hy4.y + vz4.y*hz4.y;
        float d2 = vx4.z*hx4.z + vy4.z*hy4.z + vz4.z*hz4.z;
        float d3 = vx4.w*hx4.w + vy4.w*hy4.w + vz4.w*hz4.w;
        pA[q] += acc[0]*d0 + acc[1]*d1 + acc[2]*d2 + acc[3]*d3;
      } else if (ntg < 16){
        const int f = c - (FS+FV);
        float4 t4 = *(const float4*)&tIb[f*NN + i0];
        float t0_ = acc[0]*t4.x, t1_ = acc[1]*t4.y, t2_ = acc[2]*t4.z, t3_ = acc[3]*t4.w;
        pX[q] += t0_*hx4.x + t1_*hx4.y + t2_*hx4.z + t3_*hx4.w;
        pY[q] += t0_*hy4.x + t1_*hy4.y + t2_*hy4.z + t3_*hy4.w;
        pZ[q] += t0_*hz4.x + t1_*hz4.y + t2_*hz4.z + t3_*hz4.w;
      } else {
        const int f = c - (FS+2*FV);
        float4 vx4 = *(const float4*)&vIb[(f*3+0)*NN + i0];
        float4 vy4 = *(const float4*)&vIb[(f*3+1)*NN + i0];
        float4 vz4 = *(const float4*)&vIb[(f*3+2)*NN + i0];
        pX[q] += acc[0]*vx4.x + acc[1]*vx4.y + acc[2]*vx4.z + acc[3]*vx4.w;
        pY[q] += acc[0]*vy4.x + acc[1]*vy4.y + acc[2]*vy4.z + acc[3]*vy4.w;
        pZ[q] += acc[0]*vz4.x + acc[1]*vz4.y + acc[2]*vz4.z + acc[3]*vz4.w;
      }
    }
  }

  // ---- cross-quad reduce + stage partials to LDS (per sender half) ----
  #pragma unroll
  for (int q=0;q<5;q++){
    const int ntg = q*4+wq;
    if (ntg < 12){
      float v = pA[q];
      v += __shfl_xor(v, 16, 64);
      v += __shfl_xor(v, 32, 64);
      if (lane < 16) aggP[sh][ntg*16 + lane] = v;
    } else {
      float x = pX[q]; x += __shfl_xor(x,16,64); x += __shfl_xor(x,32,64);
      float y = pY[q]; y += __shfl_xor(y,16,64); y += __shfl_xor(y,32,64);
      float z = pZ[q]; z += __shfl_xor(z,16,64); z += __shfl_xor(z,32,64);
      if (lane < 16){
        const int c = ntg*16 + lane;
        if (ntg < 16){
          const int f = c - (FS+FV);
          aggP[sh][192 + f*3+0]=x; aggP[sh][192 + f*3+1]=y; aggP[sh][192 + f*3+2]=z;
        } else {
          const int f = c - (FS+2*FV);
          aggP[sh][384 + f*3+0]=x; aggP[sh][384 + f*3+1]=y; aggP[sh][384 + f*3+2]=z;
        }
      }
    }
  }
  __syncthreads();
  for (int t2=tid; t2<576; t2+=512) aggC[t2] = (aggP[0][t2]+aggP[1][t2]) * (1.0f/128.0f);
  __syncthreads();

  const bool doOut = (WoutS != nullptr);

  // ---- epilogue: s / V updates ----
  if (tid < FS){
    float sk = sIb[tid*NN + k];
    float a0=0.f, a1=0.f;
    #pragma unroll 4
    for (int cc=0; cc<192; cc+=2){
      a0 = fmaf(aggC[cc],   WmixSl[cc*FS+tid],     a0);
      a1 = fmaf(aggC[cc+1], WmixSl[(cc+1)*FS+tid], a1);
    }
    float sn = sk + silu_f(a0+a1);
    sNew[tid] = sn;
    if (!doOut) sOut[(b*FS+tid)*NN + k] = sn;
  }
  if (tid < 192){
    const int g = tid/3, c3 = tid - g*3;
    float a0=0.f, a1=0.f;
    #pragma unroll 4
    for (int f=0; f<FV; f++){
      a0 = fmaf(aggC[192 + f*3+c3], WmixVl[f*FV+g],      a0);
      a1 = fmaf(aggC[384 + f*3+c3], WmixVl[(f+FV)*FV+g], a1);
    }
    float vn = vIb[tid*NN + k] + a0 + a1;
    vNewL[tid] = vn;
    if (!doOut) vOut[(b*FV*3 + tid)*NN + k] = vn;
  }
  __syncthreads();

  if (doOut){
    // ---- fused final output: out_v then out_s (flat concat) ----
    if (tid < FS){
      float a0=0.f, a1=0.f;
      #pragma unroll 4
      for (int f=0; f<FS; f+=2){
        a0 = fmaf(sNew[f],   WoutS[f*FS+tid],     a0);
        a1 = fmaf(sNew[f+1], WoutS[(f+1)*FS+tid], a1);
      }
      outp[BATCH*NN*FV*3 + (b*NN+k)*FS + tid] = a0+a1;
    }
    if (tid < 192){
      const int g = tid/3, c3 = tid - g*3;
      float a = comv[b*3+c3];
      #pragma unroll 4
      for (int f=0; f<FV; f++) a = fmaf(vNewL[f*3+c3], WoutV[f*FV+g], a);
      outp[(b*NN+k)*FV*3 + tid] = a;
    }
  } else if (tOut != nullptr && tid < FV){
    float a0=0.f, a1=0.f;
    #pragma unroll 4
    for (int f=0; f<FS; f+=2){
      a0 = fmaf(sNew[f],   WsvNext[f*FV+tid],     a0);
      a1 = fmaf(sNew[f+1], WsvNext[(f+1)*FV+tid], a1);
    }
    tOut[(b*FV+tid)*NN + k] = a0+a1;
  }
}

extern "C" void kernel_launch(void* const* d_in, const int* in_sizes, int n_in,
                              void* d_out, int out_size, void* d_ws, size_t ws_size,
                              hipStream_t stream)
{
  const float* x       = (const float*)d_in[0];
  const float* species = (const float*)d_in[1];
  const float* Wr1     = (const float*)d_in[2];
  const float* Wr2     = (const float*)d_in[3];
  const float* Wsv     = (const float*)d_in[4];
  const float* WmixS   = (const float*)d_in[5];
  const float* WmixV   = (const float*)d_in[6];
  const float* WoutS   = (const float*)d_in[7];
  const float* WoutV   = (const float*)d_in[8];
  float* ws  = (float*)d_ws;
  float* out = (float*)d_out;

  float* sA  = ws + OFF_SA;
  float* sB  = ws + OFF_SB;
  float* vA  = ws + OFF_VA;
  float* vB  = ws + OFF_VB;
  float* t0  = ws + OFF_T0;
  float* t1  = ws + OFF_T1;
  float* com = ws + OFF_COM;
  u16*   w2b = (u16*)(ws + OFF_W2B);

  const int initTotal = SZ_S + SZ_V + SZ_T + N_W2B + 24;
  init_kernel<<<(initTotal+255)/256, 256, 0, stream>>>(x, species, Wr2, Wsv, ws);

  // layer 0: reads sA/vA/t0, writes sB/vB and t1 (t for layer 1 from updated s)
  layer_kernel<<<BATCH*NN, 512, 0, stream>>>(x, sA, vA, t0, sB, vB, t1,
      Wr1,          w2b,            WmixS,          WmixV,          Wsv + FS*FV,
      nullptr, nullptr, nullptr, nullptr);
  // layer 1: reads sB/vB/t1, fused output epilogue writes d_out directly
  layer_kernel<<<BATCH*NN, 512, 0, stream>>>(x, sB, vB, t1, nullptr, nullptr, nullptr,
      Wr1 + NB*HID, w2b + ROUT*HID, WmixS + 192*FS, WmixV + 128*FV, nullptr,
      WoutS, WoutV, com, out);
}

// Round 6
// 220.110 us; speedup vs baseline: 3.1727x; 3.1727x over previous
//
#include <hip/hip_runtime.h>
#include <math.h>

typedef unsigned short u16;
typedef __attribute__((ext_vector_type(8))) short frag_ab;  // 8 bf16
typedef __attribute__((ext_vector_type(4))) float frag_cd;  // 4 fp32

#define BATCH 8
#define NN 128
#define FS 128
#define FV 64
#define NB 8
#define HID 64
#define ROUT 320
#define HSTRB 72    // hid bf16 LDS row stride (shorts)

// ---- ws layout (float offsets); s:[b][f][n], V:[b][f*3+c3][n], t:[b][g][n] ----
#define SZ_S (BATCH*FS*NN)
#define SZ_V (BATCH*FV*3*NN)
#define SZ_T (BATCH*FV*NN)
#define N_W2B (2*ROUT*HID)          // ushort count
#define SZ_AGG (BATCH*NN*2*576)     // edge partials [bk][half][576]
#define OFF_SA 0
#define OFF_SB (OFF_SA+SZ_S)
#define OFF_VA (OFF_SB+SZ_S)
#define OFF_VB (OFF_VA+SZ_V)
#define OFF_T0 (OFF_VB+SZ_V)
#define OFF_T1 (OFF_T0+SZ_T)
#define OFF_COM (OFF_T1+SZ_T)       // 24 floats
#define OFF_W2B (OFF_COM+24)        // N_W2B ushorts = 20480 floats
#define OFF_AGG (OFF_W2B+N_W2B/2)

__device__ __forceinline__ float silu_f(float x){ return x * (1.0f/(1.0f + __expf(-x))); }

__device__ __forceinline__ u16 f2bf(float x){
  union { float f; unsigned int u; } v; v.f = x;
  unsigned int r = v.u + 0x7fffu + ((v.u >> 16) & 1u);
  return (u16)(r >> 16);
}

__global__ void init_kernel(const float* __restrict__ x, const float* __restrict__ species,
                            const float* __restrict__ Wr2, const float* __restrict__ Wsv0,
                            float* __restrict__ ws)
{
  int idx = blockIdx.x*blockDim.x + threadIdx.x;
  const int total = SZ_S + SZ_V + SZ_T + N_W2B + 24;
  for (; idx < total; idx += gridDim.x*blockDim.x) {
    int t = idx;
    if (t < SZ_S) { int f = (t>>7)&127; ws[OFF_SA+t] = species[f]; continue; }
    t -= SZ_S;
    if (t < SZ_V) { ws[OFF_VA+t] = 0.f; continue; }
    t -= SZ_V;
    if (t < SZ_T) {
      int g = (t>>7)&63;
      float a = 0.f;
      for (int f=0; f<FS; f++) a = fmaf(species[f], Wsv0[f*FV+g], a);
      ws[OFF_T0+t] = a; continue;
    }
    t -= SZ_T;
    if (t < N_W2B) {
      // w2b[(l*320+c)*64 + j] = bf16(Wr2[l][j][c])
      int j = t & 63; int c = (t>>6)%ROUT; int l = t/(ROUT*HID);
      ((u16*)(ws+OFF_W2B))[t] = f2bf(Wr2[l*HID*ROUT + j*ROUT + c]); continue;
    }
    t -= N_W2B;
    { int bb=t/3, c3=t-bb*3;
      float a=0.f;
      for(int n=0;n<NN;n++) a += x[(bb*NN+n)*3+c3];
      ws[OFF_COM+t] = a*(1.0f/128.0f); }
  }
}

// grid = BATCH*NN*2; block 256 = 4 waves. blockIdx: bk = >>1, sender-half sh = &1.
// wave w owns 5 interleaved N-tiles (ntg = q*4+w); block covers 64 senders.
__global__ __launch_bounds__(256) void edge_kernel(
    const float* __restrict__ pos,
    const float* __restrict__ sIn,    // [b][f][n]
    const float* __restrict__ vIn,    // [b][f*3+c3][n]
    const float* __restrict__ tIn,    // [b][g][n]
    const float* __restrict__ Wr1l,   // (8,64)
    const u16*   __restrict__ w2bl,   // (320,64) bf16, c-major
    float* __restrict__ aggE)         // [bk][2][576] raw partial sums
{
  const int tid  = threadIdx.x;
  const int bk   = blockIdx.x >> 1;
  const int sh   = blockIdx.x & 1;
  const int b    = bk >> 7;
  const int k    = bk & 127;
  const int w    = tid >> 6;
  const int lane = tid & 63;
  const int col  = lane & 15;
  const int quad = lane >> 4;

  __shared__ u16   hidB[64*HSTRB];    // 9.2 KB
  __shared__ float rbL[NB][64];
  __shared__ float vhx[64], vhy[64], vhz[64];

  const float* pb = pos + b*NN*3;

  // ---- phase 0a: threads 0..63 compute geometry + rb for local sender tid ----
  if (tid < 64){
    const int i = sh*64 + tid;
    float vx = pb[k*3+0]-pb[i*3+0];
    float vy = pb[k*3+1]-pb[i*3+1];
    float vz = pb[k*3+2]-pb[i*3+2];
    float r = sqrtf(vx*vx+vy*vy+vz*vz) + 1e-8f;
    float inv = 1.0f/r;
    vhx[tid]=vx*inv; vhy[tid]=vy*inv; vhz[tid]=vz*inv;
    float u = r*0.2f;
    float env = 0.0f;
    if (u < 1.0f && i != k){
      float u2=u*u, u6=u2*u2*u2;
      env = 1.0f - 28.0f*u6 + 48.0f*u6*u - 21.0f*u6*u2;
    }
    float coef = 0.6324555320336759f * inv * env;  // 0 for self / out-of-range
    float arg  = r * 0.6283185307179586f;
    #pragma unroll
    for(int n=0;n<NB;n++) rbL[n][tid] = coef * __sinf(arg*(float)(n+1));
  }
  __syncthreads();

  // ---- phase 0b: all 256 threads: row = tid&63, quarter = tid>>6 (16 hid values) ----
  {
    const int row = tid & 63;
    const int part = tid >> 6;
    float rb[NB];
    #pragma unroll
    for(int n=0;n<NB;n++) rb[n] = rbL[n][row];
    u16* hrow = hidB + row*HSTRB;
    #pragma unroll
    for(int jg=part*4; jg<part*4+4; jg++){
      float h0=0.f,h1=0.f,h2=0.f,h3=0.f;
      #pragma unroll
      for(int n=0;n<NB;n++){
        const float* wr = Wr1l + n*HID + jg*4;
        float rn = rb[n];
        h0 = fmaf(rn, wr[0], h0);
        h1 = fmaf(rn, wr[1], h1);
        h2 = fmaf(rn, wr[2], h2);
        h3 = fmaf(rn, wr[3], h3);
      }
      ushort4 uu = make_ushort4(f2bf(silu_f(h0)), f2bf(silu_f(h1)),
                                f2bf(silu_f(h2)), f2bf(silu_f(h3)));
      *(ushort4*)(hrow + jg*4) = uu;
    }
  }

  // ---- B fragments: 5 interleaved N-tiles x 2 K-halves ----
  frag_ab bfr[5][2];
  #pragma unroll
  for (int q=0;q<5;q++){
    const int c = (q*4+w)*16 + col;
    const u16* wp = w2bl + c*HID + quad*8;
    bfr[q][0] = *(const frag_ab*)(wp);
    bfr[q][1] = *(const frag_ab*)(wp + 32);
  }

  __syncthreads();

  const float* sIb = sIn + b*FS*NN;
  const float* vIb = vIn + b*FV*3*NN;
  const float* tIb = tIn + b*FV*NN;

  float pA[5] = {0.f,0.f,0.f,0.f,0.f};
  float pX[5] = {0.f,0.f,0.f,0.f,0.f};
  float pY[5] = {0.f,0.f,0.f,0.f,0.f};
  float pZ[5] = {0.f,0.f,0.f,0.f,0.f};

  #pragma unroll
  for (int mt=0; mt<4; mt++){
    const int li0 = mt*16 + quad*4;          // local sender base for vhat
    const int i0  = sh*64 + li0;             // global sender base for factors
    const frag_ab a0 = *(const frag_ab*)&hidB[(mt*16+col)*HSTRB + quad*8];
    const frag_ab a1 = *(const frag_ab*)&hidB[(mt*16+col)*HSTRB + 32 + quad*8];
    const float4 hx4 = *(const float4*)&vhx[li0];
    const float4 hy4 = *(const float4*)&vhy[li0];
    const float4 hz4 = *(const float4*)&vhz[li0];
    #pragma unroll
    for (int q=0;q<5;q++){
      frag_cd acc = {0.f,0.f,0.f,0.f};
      acc = __builtin_amdgcn_mfma_f32_16x16x32_bf16(a0, bfr[q][0], acc, 0,0,0);
      acc = __builtin_amdgcn_mfma_f32_16x16x32_bf16(a1, bfr[q][1], acc, 0,0,0);
      const int ntg = q*4+w;
      const int c = ntg*16 + col;
      if (ntg < 8){
        float4 s4 = *(const float4*)&sIb[c*NN + i0];
        pA[q] += acc[0]*s4.x + acc[1]*s4.y + acc[2]*s4.z + acc[3]*s4.w;
      } else if (ntg < 12){
        const int f = c - FS;
        float4 vx4 = *(const float4*)&vIb[(f*3+0)*NN + i0];
        float4 vy4 = *(const float4*)&vIb[(f*3+1)*NN + i0];
        float4 vz4 = *(const float4*)&vIb[(f*3+2)*NN + i0];
        float d0 = vx4.x*hx4.x + vy4.x*hy4.x + vz4.x*hz4.x;
        float d1 = vx4.y*hx4.y + vy4.y*hy4.y + vz4.y*hz4.y;
        float d2 = vx4.z*hx4.z + vy4.z*hy4.z + vz4.z*hz4.z;
        float d3 = vx4.w*hx4.w + vy4.w*hy4.w + vz4.w*hz4.w;
        pA[q] += acc[0]*d0 + acc[1]*d1 + acc[2]*d2 + acc[3]*d3;
      } else if (ntg < 16){
        const int f = c - (FS+FV);
        float4 t4 = *(const float4*)&tIb[f*NN + i0];
        float t0_ = acc[0]*t4.x, t1_ = acc[1]*t4.y, t2_ = acc[2]*t4.z, t3_ = acc[3]*t4.w;
        pX[q] += t0_*hx4.x + t1_*hx4.y + t2_*hx4.z + t3_*hx4.w;
        pY[q] += t0_*hy4.x + t1_*hy4.y + t2_*hy4.z + t3_*hy4.w;
        pZ[q] += t0_*hz4.x + t1_*hz4.y + t2_*hz4.z + t3_*hz4.w;
      } else {
        const int f = c - (FS+2*FV);
        float4 vx4 = *(const float4*)&vIb[(f*3+0)*NN + i0];
        float4 vy4 = *(const float4*)&vIb[(f*3+1)*NN + i0];
        float4 vz4 = *(const float4*)&vIb[(f*3+2)*NN + i0];
        pX[q] += acc[0]*vx4.x + acc[1]*vx4.y + acc[2]*vx4.z + acc[3]*vx4.w;
        pY[q] += acc[0]*vy4.x + acc[1]*vy4.y + acc[2]*vy4.z + acc[3]*vy4.w;
        pZ[q] += acc[0]*vz4.x + acc[1]*vz4.y + acc[2]*vz4.z + acc[3]*vz4.w;
      }
    }
  }

  // ---- cross-quad reduce + write raw partials to global ----
  float* ag = aggE + (size_t)(bk*2 + sh)*576;
  #pragma unroll
  for (int q=0;q<5;q++){
    const int ntg = q*4+w;
    if (ntg < 12){
      float v = pA[q];
      v += __shfl_xor(v, 16, 64);
      v += __shfl_xor(v, 32, 64);
      if (lane < 16) ag[ntg*16 + lane] = v;
    } else {
      float x = pX[q]; x += __shfl_xor(x,16,64); x += __shfl_xor(x,32,64);
      float y = pY[q]; y += __shfl_xor(y,16,64); y += __shfl_xor(y,32,64);
      float z = pZ[q]; z += __shfl_xor(z,16,64); z += __shfl_xor(z,32,64);
      if (lane < 16){
        const int c = ntg*16 + lane;
        const int base = (ntg < 16) ? 192 : 384;
        const int f = c - ((ntg < 16) ? 192 : 256);
        ag[base + f*3+0]=x; ag[base + f*3+1]=y; ag[base + f*3+2]=z;
      }
    }
  }
}

// grid = BATCH*NN; block 256. Epilogue mixes for one (b,k) row.
__global__ __launch_bounds__(256) void mix_kernel(
    const float* __restrict__ aggE,   // [bk][2][576]
    const float* __restrict__ sIn,    // [b][f][n]
    const float* __restrict__ vIn,    // [b][f*3+c3][n]
    float* __restrict__ sOut,         // null on final layer
    float* __restrict__ vOut,
    float* __restrict__ tOut,         // may be null
    const float* __restrict__ WmixSl, // (192,128)
    const float* __restrict__ WmixVl, // (128,64)
    const float* __restrict__ WsvNext,// (128,64) or null
    const float* __restrict__ WoutS,  // non-null => fused final output
    const float* __restrict__ WoutV,
    const float* __restrict__ comv,
    float* __restrict__ outp)
{
  const int tid = threadIdx.x;
  const int bk  = blockIdx.x;
  const int b   = bk >> 7;
  const int k   = bk & 127;

  __shared__ float aggC[576];
  __shared__ float sNew[FS];
  __shared__ float vNewL[192];

  const float* ag = aggE + (size_t)bk*1152;
  for (int idx=tid; idx<576; idx+=256)
    aggC[idx] = (ag[idx] + ag[576+idx]) * (1.0f/128.0f);
  __syncthreads();

  const float* sIb = sIn + b*FS*NN;
  const float* vIb = vIn + b*FV*3*NN;
  const bool doOut = (WoutS != nullptr);

  if (tid < FS){
    float sk = sIb[tid*NN + k];
    float a0=0.f, a1=0.f, a2=0.f, a3=0.f;
    #pragma unroll 8
    for (int cc=0; cc<192; cc+=4){
      a0 = fmaf(aggC[cc],   WmixSl[cc*FS+tid],     a0);
      a1 = fmaf(aggC[cc+1], WmixSl[(cc+1)*FS+tid], a1);
      a2 = fmaf(aggC[cc+2], WmixSl[(cc+2)*FS+tid], a2);
      a3 = fmaf(aggC[cc+3], WmixSl[(cc+3)*FS+tid], a3);
    }
    float sn = sk + silu_f((a0+a1)+(a2+a3));
    sNew[tid] = sn;
    if (!doOut) sOut[(b*FS+tid)*NN + k] = sn;
  }
  if (tid < 192){
    const int g = tid/3, c3 = tid - g*3;
    float a0=0.f, a1=0.f, a2=0.f, a3=0.f;
    #pragma unroll 8
    for (int f=0; f<FV; f+=2){
      a0 = fmaf(aggC[192 + f*3+c3],     WmixVl[f*FV+g],        a0);
      a1 = fmaf(aggC[384 + f*3+c3],     WmixVl[(f+FV)*FV+g],   a1);
      a2 = fmaf(aggC[192 + (f+1)*3+c3], WmixVl[(f+1)*FV+g],    a2);
      a3 = fmaf(aggC[384 + (f+1)*3+c3], WmixVl[(f+1+FV)*FV+g], a3);
    }
    float vn = vIb[tid*NN + k] + (a0+a1)+(a2+a3);
    vNewL[tid] = vn;
    if (!doOut) vOut[(b*FV*3 + tid)*NN + k] = vn;
  }
  __syncthreads();

  if (doOut){
    if (tid < FS){
      float a0=0.f, a1=0.f, a2=0.f, a3=0.f;
      #pragma unroll 8
      for (int f=0; f<FS; f+=4){
        a0 = fmaf(sNew[f],   WoutS[f*FS+tid],     a0);
        a1 = fmaf(sNew[f+1], WoutS[(f+1)*FS+tid], a1);
        a2 = fmaf(sNew[f+2], WoutS[(f+2)*FS+tid], a2);
        a3 = fmaf(sNew[f+3], WoutS[(f+3)*FS+tid], a3);
      }
      outp[BATCH*NN*FV*3 + (b*NN+k)*FS + tid] = (a0+a1)+(a2+a3);
    }
    if (tid < 192){
      const int g = tid/3, c3 = tid - g*3;
      float a = comv[b*3+c3];
      #pragma unroll 8
      for (int f=0; f<FV; f++) a = fmaf(vNewL[f*3+c3], WoutV[f*FV+g], a);
      outp[(b*NN+k)*FV*3 + tid] = a;
    }
  } else if (tOut != nullptr && tid < FV){
    float a0=0.f, a1=0.f, a2=0.f, a3=0.f;
    #pragma unroll 8
    for (int f=0; f<FS; f+=4){
      a0 = fmaf(sNew[f],   WsvNext[f*FV+tid],     a0);
      a1 = fmaf(sNew[f+1], WsvNext[(f+1)*FV+tid], a1);
      a2 = fmaf(sNew[f+2], WsvNext[(f+2)*FV+tid], a2);
      a3 = fmaf(sNew[f+3], WsvNext[(f+3)*FV+tid], a3);
    }
    tOut[(b*FV+tid)*NN + k] = (a0+a1)+(a2+a3);
  }
}

extern "C" void kernel_launch(void* const* d_in, const int* in_sizes, int n_in,
                              void* d_out, int out_size, void* d_ws, size_t ws_size,
                              hipStream_t stream)
{
  const float* x       = (const float*)d_in[0];
  const float* species = (const float*)d_in[1];
  const float* Wr1     = (const float*)d_in[2];
  const float* Wr2     = (const float*)d_in[3];
  const float* Wsv     = (const float*)d_in[4];
  const float* WmixS   = (const float*)d_in[5];
  const float* WmixV   = (const float*)d_in[6];
  const float* WoutS   = (const float*)d_in[7];
  const float* WoutV   = (const float*)d_in[8];
  float* ws  = (float*)d_ws;
  float* out = (float*)d_out;

  float* sA  = ws + OFF_SA;
  float* sB  = ws + OFF_SB;
  float* vA  = ws + OFF_VA;
  float* vB  = ws + OFF_VB;
  float* t0  = ws + OFF_T0;
  float* t1  = ws + OFF_T1;
  float* com = ws + OFF_COM;
  u16*   w2b = (u16*)(ws + OFF_W2B);
  float* agg = ws + OFF_AGG;

  const int initTotal = SZ_S + SZ_V + SZ_T + N_W2B + 24;
  init_kernel<<<(initTotal+255)/256, 256, 0, stream>>>(x, species, Wr2, Wsv, ws);

  // layer 0
  edge_kernel<<<BATCH*NN*2, 256, 0, stream>>>(x, sA, vA, t0, Wr1, w2b, agg);
  mix_kernel<<<BATCH*NN, 256, 0, stream>>>(agg, sA, vA, sB, vB, t1,
      WmixS, WmixV, Wsv + FS*FV, nullptr, nullptr, nullptr, nullptr);
  // layer 1 (fused final output)
  edge_kernel<<<BATCH*NN*2, 256, 0, stream>>>(x, sB, vB, t1, Wr1 + NB*HID, w2b + ROUT*HID, agg);
  mix_kernel<<<BATCH*NN, 256, 0, stream>>>(agg, sB, vB, nullptr, nullptr, nullptr,
      WmixS + 192*FS, WmixV + 128*FV, nullptr, WoutS, WoutV, com, out);
}

// Round 7
// 208.402 us; speedup vs baseline: 3.3509x; 1.0562x over previous
//
#include <hip/hip_runtime.h>
#include <math.h>

typedef unsigned short u16;
typedef __attribute__((ext_vector_type(8))) short frag_ab;  // 8 bf16
typedef __attribute__((ext_vector_type(4))) float frag_cd;  // 4 fp32

#define BATCH 8
#define NN 128
#define FS 128
#define FV 64
#define NB 8
#define HID 64
#define ROUT 320
#define HSTRB 72    // hid bf16 LDS row stride (shorts)

// ---- ws layout (float offsets); s:[b][f][n], V:[b][f*3+c3][n], t:[b][g][n] ----
#define SZ_S (BATCH*FS*NN)
#define SZ_V (BATCH*FV*3*NN)
#define SZ_T (BATCH*FV*NN)
#define N_W2B (2*ROUT*HID)          // ushort count
#define SZ_AGG (BATCH*NN*2*576)     // edge partials [bk][half][576]
#define OFF_SA 0
#define OFF_SB (OFF_SA+SZ_S)
#define OFF_VA (OFF_SB+SZ_S)
#define OFF_VB (OFF_VA+SZ_V)
#define OFF_T0 (OFF_VB+SZ_V)
#define OFF_T1 (OFF_T0+SZ_T)
#define OFF_COM (OFF_T1+SZ_T)       // 24 floats
#define OFF_W2B (OFF_COM+24)        // N_W2B ushorts = 20480 floats
#define OFF_AGG (OFF_W2B+N_W2B/2)

__device__ __forceinline__ float silu_f(float x){ return x * (1.0f/(1.0f + __expf(-x))); }

__device__ __forceinline__ u16 f2bf(float x){
  union { float f; unsigned int u; } v; v.f = x;
  unsigned int r = v.u + 0x7fffu + ((v.u >> 16) & 1u);
  return (u16)(r >> 16);
}

__global__ void init_kernel(const float* __restrict__ x, const float* __restrict__ species,
                            const float* __restrict__ Wr2, const float* __restrict__ Wsv0,
                            float* __restrict__ ws)
{
  int idx = blockIdx.x*blockDim.x + threadIdx.x;
  const int total = SZ_S + SZ_V + SZ_T + N_W2B + 24;
  for (; idx < total; idx += gridDim.x*blockDim.x) {
    int t = idx;
    if (t < SZ_S) { int f = (t>>7)&127; ws[OFF_SA+t] = species[f]; continue; }
    t -= SZ_S;
    if (t < SZ_V) { ws[OFF_VA+t] = 0.f; continue; }
    t -= SZ_V;
    if (t < SZ_T) {
      int g = (t>>7)&63;
      float a = 0.f;
      for (int f=0; f<FS; f++) a = fmaf(species[f], Wsv0[f*FV+g], a);
      ws[OFF_T0+t] = a; continue;
    }
    t -= SZ_T;
    if (t < N_W2B) {
      // w2b[(l*320+c)*64 + j] = bf16(Wr2[l][j][c])
      int j = t & 63; int c = (t>>6)%ROUT; int l = t/(ROUT*HID);
      ((u16*)(ws+OFF_W2B))[t] = f2bf(Wr2[l*HID*ROUT + j*ROUT + c]); continue;
    }
    t -= N_W2B;
    { int bb=t/3, c3=t-bb*3;
      float a=0.f;
      for(int n=0;n<NN;n++) a += x[(bb*NN+n)*3+c3];
      ws[OFF_COM+t] = a*(1.0f/128.0f); }
  }
}

// grid = BATCH*NN*2; block 256 = 4 waves. blockIdx: bk = >>1, sender-half sh = &1.
// q-outer main loop: wave w handles tile ntg=q*4+w per q; B-frags loaded per q
// (keeps ~8 B-VGPRs live instead of 40 -> natural VGPR<=64 for 8 blocks/CU).
__global__ __launch_bounds__(256) void edge_kernel(
    const float* __restrict__ pos,
    const float* __restrict__ sIn,    // [b][f][n]
    const float* __restrict__ vIn,    // [b][f*3+c3][n]
    const float* __restrict__ tIn,    // [b][g][n]
    const float* __restrict__ Wr1l,   // (8,64)
    const u16*   __restrict__ w2bl,   // (320,64) bf16, c-major
    float* __restrict__ aggE)         // [bk][2][576] raw partial sums
{
  const int tid  = threadIdx.x;
  const int bk   = blockIdx.x >> 1;
  const int sh   = blockIdx.x & 1;
  const int b    = bk >> 7;
  const int k    = bk & 127;
  const int w    = tid >> 6;
  const int lane = tid & 63;
  const int col  = lane & 15;
  const int quad = lane >> 4;

  __shared__ u16   hidB[64*HSTRB];    // 9.2 KB
  __shared__ float rbL[NB][64];
  __shared__ float vhx[64], vhy[64], vhz[64];

  const float* pb = pos + b*NN*3;

  // ---- phase 0a: threads 0..63 compute geometry + rb for local sender tid ----
  if (tid < 64){
    const int i = sh*64 + tid;
    float vx = pb[k*3+0]-pb[i*3+0];
    float vy = pb[k*3+1]-pb[i*3+1];
    float vz = pb[k*3+2]-pb[i*3+2];
    float r = sqrtf(vx*vx+vy*vy+vz*vz) + 1e-8f;
    float inv = 1.0f/r;
    vhx[tid]=vx*inv; vhy[tid]=vy*inv; vhz[tid]=vz*inv;
    float u = r*0.2f;
    float env = 0.0f;
    if (u < 1.0f && i != k){
      float u2=u*u, u6=u2*u2*u2;
      env = 1.0f - 28.0f*u6 + 48.0f*u6*u - 21.0f*u6*u2;
    }
    float coef = 0.6324555320336759f * inv * env;  // 0 for self / out-of-range
    float arg  = r * 0.6283185307179586f;
    #pragma unroll
    for(int n=0;n<NB;n++) rbL[n][tid] = coef * __sinf(arg*(float)(n+1));
  }
  __syncthreads();

  // ---- phase 0b: all 256 threads: row = tid&63, quarter = tid>>6 (16 hid values) ----
  {
    const int row = tid & 63;
    const int part = tid >> 6;
    float rb[NB];
    #pragma unroll
    for(int n=0;n<NB;n++) rb[n] = rbL[n][row];
    u16* hrow = hidB + row*HSTRB;
    #pragma unroll
    for(int jg=part*4; jg<part*4+4; jg++){
      float h0=0.f,h1=0.f,h2=0.f,h3=0.f;
      #pragma unroll
      for(int n=0;n<NB;n++){
        const float* wr = Wr1l + n*HID + jg*4;
        float rn = rb[n];
        h0 = fmaf(rn, wr[0], h0);
        h1 = fmaf(rn, wr[1], h1);
        h2 = fmaf(rn, wr[2], h2);
        h3 = fmaf(rn, wr[3], h3);
      }
      ushort4 uu = make_ushort4(f2bf(silu_f(h0)), f2bf(silu_f(h1)),
                                f2bf(silu_f(h2)), f2bf(silu_f(h3)));
      *(ushort4*)(hrow + jg*4) = uu;
    }
  }
  __syncthreads();

  const float* sIb = sIn + b*FS*NN;
  const float* vIb = vIn + b*FV*3*NN;
  const float* tIb = tIn + b*FV*NN;
  const int i00 = sh*64 + quad*4;      // global sender offset within a feature row
  const int l00 = quad*4;              // local sender offset for vhat
  float* ag = aggE + (size_t)(bk*2 + sh)*576;

  for (int q=0; q<5; q++){
    const int ntg = q*4 + w;
    const int c   = ntg*16 + col;
    const u16* wp = w2bl + c*HID + quad*8;
    const frag_ab b0 = *(const frag_ab*)(wp);
    const frag_ab b1 = *(const frag_ab*)(wp + 32);

    if (ntg < 8){
      // m0a: fac = s[i][c]
      const float* fb = sIb + c*NN + i00;
      float sA = 0.f;
      #pragma unroll
      for (int mt=0; mt<4; mt++){
        frag_ab a0 = *(const frag_ab*)&hidB[(mt*16+col)*HSTRB + quad*8];
        frag_ab a1 = *(const frag_ab*)&hidB[(mt*16+col)*HSTRB + 32 + quad*8];
        frag_cd acc = {0.f,0.f,0.f,0.f};
        acc = __builtin_amdgcn_mfma_f32_16x16x32_bf16(a0, b0, acc, 0,0,0);
        acc = __builtin_amdgcn_mfma_f32_16x16x32_bf16(a1, b1, acc, 0,0,0);
        float4 s4 = *(const float4*)&fb[mt*16];
        sA += acc[0]*s4.x + acc[1]*s4.y + acc[2]*s4.z + acc[3]*s4.w;
      }
      sA += __shfl_xor(sA, 16, 64);
      sA += __shfl_xor(sA, 32, 64);
      if (lane < 16) ag[ntg*16 + lane] = sA;
    } else if (ntg < 12){
      // m0b: fac = V[i,f,:]·vhat[i]
      const int f = c - FS;
      const float* fb = vIb + f*3*NN + i00;
      float sA = 0.f;
      #pragma unroll
      for (int mt=0; mt<4; mt++){
        frag_ab a0 = *(const frag_ab*)&hidB[(mt*16+col)*HSTRB + quad*8];
        frag_ab a1 = *(const frag_ab*)&hidB[(mt*16+col)*HSTRB + 32 + quad*8];
        frag_cd acc = {0.f,0.f,0.f,0.f};
        acc = __builtin_amdgcn_mfma_f32_16x16x32_bf16(a0, b0, acc, 0,0,0);
        acc = __builtin_amdgcn_mfma_f32_16x16x32_bf16(a1, b1, acc, 0,0,0);
        float4 vx4 = *(const float4*)&fb[mt*16];
        float4 vy4 = *(const float4*)&fb[NN + mt*16];
        float4 vz4 = *(const float4*)&fb[2*NN + mt*16];
        float4 hx4 = *(const float4*)&vhx[l00 + mt*16];
        float4 hy4 = *(const float4*)&vhy[l00 + mt*16];
        float4 hz4 = *(const float4*)&vhz[l00 + mt*16];
        float d0 = vx4.x*hx4.x + vy4.x*hy4.x + vz4.x*hz4.x;
        float d1 = vx4.y*hx4.y + vy4.y*hy4.y + vz4.y*hz4.y;
        float d2 = vx4.z*hx4.z + vy4.z*hy4.z + vz4.z*hz4.z;
        float d3 = vx4.w*hx4.w + vy4.w*hy4.w + vz4.w*hz4.w;
        sA += acc[0]*d0 + acc[1]*d1 + acc[2]*d2 + acc[3]*d3;
      }
      sA += __shfl_xor(sA, 16, 64);
      sA += __shfl_xor(sA, 32, 64);
      if (lane < 16) ag[ntg*16 + lane] = sA;
    } else if (ntg < 16){
      // m1a: tb = H * t[i,f]; 3 components via vhat
      const int f = c - (FS+FV);
      const float* fb = tIb + f*NN + i00;
      float sX=0.f, sY=0.f, sZ=0.f;
      #pragma unroll
      for (int mt=0; mt<4; mt++){
        frag_ab a0 = *(const frag_ab*)&hidB[(mt*16+col)*HSTRB + quad*8];
        frag_ab a1 = *(const frag_ab*)&hidB[(mt*16+col)*HSTRB + 32 + quad*8];
        frag_cd acc = {0.f,0.f,0.f,0.f};
        acc = __builtin_amdgcn_mfma_f32_16x16x32_bf16(a0, b0, acc, 0,0,0);
        acc = __builtin_amdgcn_mfma_f32_16x16x32_bf16(a1, b1, acc, 0,0,0);
        float4 t4 = *(const float4*)&fb[mt*16];
        float4 hx4 = *(const float4*)&vhx[l00 + mt*16];
        float4 hy4 = *(const float4*)&vhy[l00 + mt*16];
        float4 hz4 = *(const float4*)&vhz[l00 + mt*16];
        float t0_ = acc[0]*t4.x, t1_ = acc[1]*t4.y, t2_ = acc[2]*t4.z, t3_ = acc[3]*t4.w;
        sX += t0_*hx4.x + t1_*hx4.y + t2_*hx4.z + t3_*hx4.w;
        sY += t0_*hy4.x + t1_*hy4.y + t2_*hy4.z + t3_*hy4.w;
        sZ += t0_*hz4.x + t1_*hz4.y + t2_*hz4.z + t3_*hz4.w;
      }
      sX += __shfl_xor(sX,16,64); sX += __shfl_xor(sX,32,64);
      sY += __shfl_xor(sY,16,64); sY += __shfl_xor(sY,32,64);
      sZ += __shfl_xor(sZ,16,64); sZ += __shfl_xor(sZ,32,64);
      if (lane < 16){
        const int f2 = (ntg*16 + lane) - 192;
        ag[192 + f2*3+0]=sX; ag[192 + f2*3+1]=sY; ag[192 + f2*3+2]=sZ;
      }
    } else {
      // m1b: fac = V[i,f,c3]
      const int f = c - (FS+2*FV);
      const float* fb = vIb + f*3*NN + i00;
      float sX=0.f, sY=0.f, sZ=0.f;
      #pragma unroll
      for (int mt=0; mt<4; mt++){
        frag_ab a0 = *(const frag_ab*)&hidB[(mt*16+col)*HSTRB + quad*8];
        frag_ab a1 = *(const frag_ab*)&hidB[(mt*16+col)*HSTRB + 32 + quad*8];
        frag_cd acc = {0.f,0.f,0.f,0.f};
        acc = __builtin_amdgcn_mfma_f32_16x16x32_bf16(a0, b0, acc, 0,0,0);
        acc = __builtin_amdgcn_mfma_f32_16x16x32_bf16(a1, b1, acc, 0,0,0);
        float4 vx4 = *(const float4*)&fb[mt*16];
        float4 vy4 = *(const float4*)&fb[NN + mt*16];
        float4 vz4 = *(const float4*)&fb[2*NN + mt*16];
        sX += acc[0]*vx4.x + acc[1]*vx4.y + acc[2]*vx4.z + acc[3]*vx4.w;
        sY += acc[0]*vy4.x + acc[1]*vy4.y + acc[2]*vy4.z + acc[3]*vy4.w;
        sZ += acc[0]*vz4.x + acc[1]*vz4.y + acc[2]*vz4.z + acc[3]*vz4.w;
      }
      sX += __shfl_xor(sX,16,64); sX += __shfl_xor(sX,32,64);
      sY += __shfl_xor(sY,16,64); sY += __shfl_xor(sY,32,64);
      sZ += __shfl_xor(sZ,16,64); sZ += __shfl_xor(sZ,32,64);
      if (lane < 16){
        const int f2 = (ntg*16 + lane) - 256;
        ag[384 + f2*3+0]=sX; ag[384 + f2*3+1]=sY; ag[384 + f2*3+2]=sZ;
      }
    }
  }
}

// grid = BATCH*NN; block 256. Epilogue mixes for one (b,k) row.
__global__ __launch_bounds__(256) void mix_kernel(
    const float* __restrict__ aggE,   // [bk][2][576]
    const float* __restrict__ sIn,    // [b][f][n]
    const float* __restrict__ vIn,    // [b][f*3+c3][n]
    float* __restrict__ sOut,         // null on final layer
    float* __restrict__ vOut,
    float* __restrict__ tOut,         // may be null
    const float* __restrict__ WmixSl, // (192,128)
    const float* __restrict__ WmixVl, // (128,64)
    const float* __restrict__ WsvNext,// (128,64) or null
    const float* __restrict__ WoutS,  // non-null => fused final output
    const float* __restrict__ WoutV,
    const float* __restrict__ comv,
    float* __restrict__ outp)
{
  const int tid = threadIdx.x;
  const int bk  = blockIdx.x;
  const int b   = bk >> 7;
  const int k   = bk & 127;

  __shared__ float aggC[576];
  __shared__ float sNew[FS];
  __shared__ float vNewL[192];

  const float* ag = aggE + (size_t)bk*1152;
  for (int idx=tid; idx<576; idx+=256)
    aggC[idx] = (ag[idx] + ag[576+idx]) * (1.0f/128.0f);
  __syncthreads();

  const float* sIb = sIn + b*FS*NN;
  const float* vIb = vIn + b*FV*3*NN;
  const bool doOut = (WoutS != nullptr);

  if (tid < FS){
    float sk = sIb[tid*NN + k];
    float a0=0.f, a1=0.f, a2=0.f, a3=0.f;
    #pragma unroll 8
    for (int cc=0; cc<192; cc+=4){
      a0 = fmaf(aggC[cc],   WmixSl[cc*FS+tid],     a0);
      a1 = fmaf(aggC[cc+1], WmixSl[(cc+1)*FS+tid], a1);
      a2 = fmaf(aggC[cc+2], WmixSl[(cc+2)*FS+tid], a2);
      a3 = fmaf(aggC[cc+3], WmixSl[(cc+3)*FS+tid], a3);
    }
    float sn = sk + silu_f((a0+a1)+(a2+a3));
    sNew[tid] = sn;
    if (!doOut) sOut[(b*FS+tid)*NN + k] = sn;
  }
  if (tid < 192){
    const int g = tid/3, c3 = tid - g*3;
    float a0=0.f, a1=0.f, a2=0.f, a3=0.f;
    #pragma unroll 8
    for (int f=0; f<FV; f+=2){
      a0 = fmaf(aggC[192 + f*3+c3],     WmixVl[f*FV+g],        a0);
      a1 = fmaf(aggC[384 + f*3+c3],     WmixVl[(f+FV)*FV+g],   a1);
      a2 = fmaf(aggC[192 + (f+1)*3+c3], WmixVl[(f+1)*FV+g],    a2);
      a3 = fmaf(aggC[384 + (f+1)*3+c3], WmixVl[(f+1+FV)*FV+g], a3);
    }
    float vn = vIb[tid*NN + k] + (a0+a1)+(a2+a3);
    vNewL[tid] = vn;
    if (!doOut) vOut[(b*FV*3 + tid)*NN + k] = vn;
  }
  __syncthreads();

  if (doOut){
    if (tid < FS){
      float a0=0.f, a1=0.f, a2=0.f, a3=0.f;
      #pragma unroll 8
      for (int f=0; f<FS; f+=4){
        a0 = fmaf(sNew[f],   WoutS[f*FS+tid],     a0);
        a1 = fmaf(sNew[f+1], WoutS[(f+1)*FS+tid], a1);
        a2 = fmaf(sNew[f+2], WoutS[(f+2)*FS+tid], a2);
        a3 = fmaf(sNew[f+3], WoutS[(f+3)*FS+tid], a3);
      }
      outp[BATCH*NN*FV*3 + (b*NN+k)*FS + tid] = (a0+a1)+(a2+a3);
    }
    if (tid < 192){
      const int g = tid/3, c3 = tid - g*3;
      float a = comv[b*3+c3];
      #pragma unroll 8
      for (int f=0; f<FV; f++) a = fmaf(vNewL[f*3+c3], WoutV[f*FV+g], a);
      outp[(b*NN+k)*FV*3 + tid] = a;
    }
  } else if (tOut != nullptr && tid < FV){
    float a0=0.f, a1=0.f, a2=0.f, a3=0.f;
    #pragma unroll 8
    for (int f=0; f<FS; f+=4){
      a0 = fmaf(sNew[f],   WsvNext[f*FV+tid],     a0);
      a1 = fmaf(sNew[f+1], WsvNext[(f+1)*FV+tid], a1);
      a2 = fmaf(sNew[f+2], WsvNext[(f+2)*FV+tid], a2);
      a3 = fmaf(sNew[f+3], WsvNext[(f+3)*FV+tid], a3);
    }
    tOut[(b*FV+tid)*NN + k] = (a0+a1)+(a2+a3);
  }
}

extern "C" void kernel_launch(void* const* d_in, const int* in_sizes, int n_in,
                              void* d_out, int out_size, void* d_ws, size_t ws_size,
                              hipStream_t stream)
{
  const float* x       = (const float*)d_in[0];
  const float* species = (const float*)d_in[1];
  const float* Wr1     = (const float*)d_in[2];
  const float* Wr2     = (const float*)d_in[3];
  const float* Wsv     = (const float*)d_in[4];
  const float* WmixS   = (const float*)d_in[5];
  const float* WmixV   = (const float*)d_in[6];
  const float* WoutS   = (const float*)d_in[7];
  const float* WoutV   = (const float*)d_in[8];
  float* ws  = (float*)d_ws;
  float* out = (float*)d_out;

  float* sA  = ws + OFF_SA;
  float* sB  = ws + OFF_SB;
  float* vA  = ws + OFF_VA;
  float* vB  = ws + OFF_VB;
  float* t0  = ws + OFF_T0;
  float* t1  = ws + OFF_T1;
  float* com = ws + OFF_COM;
  u16*   w2b = (u16*)(ws + OFF_W2B);
  float* agg = ws + OFF_AGG;

  const int initTotal = SZ_S + SZ_V + SZ_T + N_W2B + 24;
  init_kernel<<<(initTotal+255)/256, 256, 0, stream>>>(x, species, Wr2, Wsv, ws);

  // layer 0
  edge_kernel<<<BATCH*NN*2, 256, 0, stream>>>(x, sA, vA, t0, Wr1, w2b, agg);
  mix_kernel<<<BATCH*NN, 256, 0, stream>>>(agg, sA, vA, sB, vB, t1,
      WmixS, WmixV, Wsv + FS*FV, nullptr, nullptr, nullptr, nullptr);
  // layer 1 (fused final output)
  edge_kernel<<<BATCH*NN*2, 256, 0, stream>>>(x, sB, vB, t1, Wr1 + NB*HID, w2b + ROUT*HID, agg);
  mix_kernel<<<BATCH*NN, 256, 0, stream>>>(agg, sB, vB, nullptr, nullptr, nullptr,
      WmixS + 192*FS, WmixV + 128*FV, nullptr, WoutS, WoutV, com, out);
}

// Round 8
// 205.718 us; speedup vs baseline: 3.3946x; 1.0130x over previous
//
#include <hip/hip_runtime.h>
#include <math.h>

typedef unsigned short u16;
typedef __attribute__((ext_vector_type(8))) short frag_ab;  // 8 bf16
typedef __attribute__((ext_vector_type(4))) float frag_cd;  // 4 fp32

#define BATCH 8
#define NN 128
#define FS 128
#define FV 64
#define NB 8
#define HID 64
#define ROUT 320
#define HSTRB 72    // hid bf16 LDS row stride (shorts)

// ---- ws layout (float offsets); s:[b][f][n], V:[b][f*3+c3][n], t:[b][g][n] ----
#define SZ_S (BATCH*FS*NN)
#define SZ_V (BATCH*FV*3*NN)
#define SZ_T (BATCH*FV*NN)
#define N_W2B (2*ROUT*HID)          // ushort count
#define OFF_SA 0
#define OFF_SB (OFF_SA+SZ_S)
#define OFF_VA (OFF_SB+SZ_S)
#define OFF_VB (OFF_VA+SZ_V)
#define OFF_T0 (OFF_VB+SZ_V)
#define OFF_T1 (OFF_T0+SZ_T)
#define OFF_COM (OFF_T1+SZ_T)       // 24 floats
#define OFF_W2B (OFF_COM+24)        // N_W2B ushorts = 20480 floats

__device__ __forceinline__ float silu_f(float x){ return x * (1.0f/(1.0f + __expf(-x))); }

__device__ __forceinline__ u16 f2bf(float x){
  union { float f; unsigned int u; } v; v.f = x;
  unsigned int r = v.u + 0x7fffu + ((v.u >> 16) & 1u);
  return (u16)(r >> 16);
}

__global__ void init_kernel(const float* __restrict__ x, const float* __restrict__ species,
                            const float* __restrict__ Wr2, const float* __restrict__ Wsv0,
                            float* __restrict__ ws)
{
  int idx = blockIdx.x*blockDim.x + threadIdx.x;
  const int total = SZ_S + SZ_V + SZ_T + N_W2B + 24;
  for (; idx < total; idx += gridDim.x*blockDim.x) {
    int t = idx;
    if (t < SZ_S) { int f = (t>>7)&127; ws[OFF_SA+t] = species[f]; continue; }
    t -= SZ_S;
    if (t < SZ_V) { ws[OFF_VA+t] = 0.f; continue; }
    t -= SZ_V;
    if (t < SZ_T) {
      int g = (t>>7)&63;
      float a = 0.f;
      for (int f=0; f<FS; f++) a = fmaf(species[f], Wsv0[f*FV+g], a);
      ws[OFF_T0+t] = a; continue;
    }
    t -= SZ_T;
    if (t < N_W2B) {
      // w2b[(l*320+c)*64 + j] = bf16(Wr2[l][j][c])
      int j = t & 63; int c = (t>>6)%ROUT; int l = t/(ROUT*HID);
      ((u16*)(ws+OFF_W2B))[t] = f2bf(Wr2[l*HID*ROUT + j*ROUT + c]); continue;
    }
    t -= N_W2B;
    { int bb=t/3, c3=t-bb*3;
      float a=0.f;
      for(int n=0;n<NN;n++) a += x[(bb*NN+n)*3+c3];
      ws[OFF_COM+t] = a*(1.0f/128.0f); }
  }
}

// one block per (batch, receiver k); 512 threads = 8 waves.
// wave w: wq=w&3 channel group (tiles ntg=q*4+wq), sh=w>>2 sender half.
// q-outer JIT B-frag loads (proven VGPR<=64 body). NO min-waves bound (spill hazard).
__global__ __launch_bounds__(512) void layer_kernel(
    const float* __restrict__ pos,
    const float* __restrict__ sIn,    // [b][f][n]
    const float* __restrict__ vIn,    // [b][f*3+c3][n]
    const float* __restrict__ tIn,    // [b][g][n]
    float* __restrict__ sOut,         // null on final layer
    float* __restrict__ vOut,
    float* __restrict__ tOut,         // may be null
    const float* __restrict__ Wr1l,   // (8,64)
    const u16*   __restrict__ w2bl,   // (320,64) bf16, c-major
    const float* __restrict__ WmixSl, // (192,128)
    const float* __restrict__ WmixVl, // (128,64)
    const float* __restrict__ WsvNext,// (128,64) or null
    const float* __restrict__ WoutS,  // non-null => fused final output
    const float* __restrict__ WoutV,
    const float* __restrict__ comv,
    float* __restrict__ outp)
{
  const int tid  = threadIdx.x;
  const int b    = blockIdx.x >> 7;
  const int k    = blockIdx.x & 127;
  const int w    = tid >> 6;
  const int lane = tid & 63;
  const int col  = lane & 15;
  const int quad = lane >> 4;
  const int wq   = w & 3;       // channel group
  const int sh   = w >> 2;      // sender half

  __shared__ u16   hidB[128*HSTRB];           // 18.4 KB
  __shared__ float vhx[128], vhy[128], vhz[128];
  __shared__ float aggP[2][576];
  __shared__ float aggC[576];
  __shared__ float sNew[FS];
  __shared__ float vNewL[192];

  const float* pb = pos + b*NN*3;

  // ---- phase 0: threads 0..255, thread t computes half a hid row for sender i=t&127 ----
  if (tid < 256){
    const int i    = tid & 127;
    const int half = tid >> 7;
    float vx = pb[k*3+0]-pb[i*3+0];
    float vy = pb[k*3+1]-pb[i*3+1];
    float vz = pb[k*3+2]-pb[i*3+2];
    float r = sqrtf(vx*vx+vy*vy+vz*vz) + 1e-8f;
    float inv = 1.0f/r;
    if (half==0){ vhx[i]=vx*inv; vhy[i]=vy*inv; vhz[i]=vz*inv; }
    float u = r*0.2f;
    float env = 0.0f;
    if (u < 1.0f && i != k){
      float u2=u*u, u6=u2*u2*u2;
      env = 1.0f - 28.0f*u6 + 48.0f*u6*u - 21.0f*u6*u2;
    }
    float coef = 0.6324555320336759f * inv * env;  // 0 for self / out-of-range
    float arg  = r * 0.6283185307179586f;
    float rb[NB];
    #pragma unroll
    for(int n=0;n<NB;n++) rb[n] = coef * __sinf(arg*(float)(n+1));
    u16* hrow = hidB + i*HSTRB;
    #pragma unroll
    for(int jg=0;jg<8;jg++){
      const int jgg = half*8 + jg;
      float h0=0.f,h1=0.f,h2=0.f,h3=0.f;
      #pragma unroll
      for(int n=0;n<NB;n++){
        const float* wr = Wr1l + n*HID + jgg*4;
        float rn = rb[n];
        h0 = fmaf(rn, wr[0], h0);
        h1 = fmaf(rn, wr[1], h1);
        h2 = fmaf(rn, wr[2], h2);
        h3 = fmaf(rn, wr[3], h3);
      }
      ushort4 uu = make_ushort4(f2bf(silu_f(h0)), f2bf(silu_f(h1)),
                                f2bf(silu_f(h2)), f2bf(silu_f(h3)));
      *(ushort4*)(hrow + jgg*4) = uu;
    }
  }
  __syncthreads();

  const float* sIb = sIn + b*FS*NN;
  const float* vIb = vIn + b*FV*3*NN;
  const float* tIb = tIn + b*FV*NN;
  const int i00 = sh*64 + quad*4;      // global sender offset within a feature row

  for (int q=0; q<5; q++){
    const int ntg = q*4 + wq;
    const int c   = ntg*16 + col;
    const u16* wp = w2bl + c*HID + quad*8;
    const frag_ab b0 = *(const frag_ab*)(wp);
    const frag_ab b1 = *(const frag_ab*)(wp + 32);

    if (ntg < 8){
      // m0a: fac = s[i][c]
      const float* fb = sIb + c*NN + i00;
      float sA = 0.f;
      #pragma unroll
      for (int mt=0; mt<4; mt++){
        const int hrow = (sh*64 + mt*16 + col)*HSTRB + quad*8;
        frag_ab a0 = *(const frag_ab*)&hidB[hrow];
        frag_ab a1 = *(const frag_ab*)&hidB[hrow + 32];
        frag_cd acc = {0.f,0.f,0.f,0.f};
        acc = __builtin_amdgcn_mfma_f32_16x16x32_bf16(a0, b0, acc, 0,0,0);
        acc = __builtin_amdgcn_mfma_f32_16x16x32_bf16(a1, b1, acc, 0,0,0);
        float4 s4 = *(const float4*)&fb[mt*16];
        sA += acc[0]*s4.x + acc[1]*s4.y + acc[2]*s4.z + acc[3]*s4.w;
      }
      sA += __shfl_xor(sA, 16, 64);
      sA += __shfl_xor(sA, 32, 64);
      if (lane < 16) aggP[sh][ntg*16 + lane] = sA;
    } else if (ntg < 12){
      // m0b: fac = V[i,f,:]·vhat[i]
      const int f = c - FS;
      const float* fb = vIb + f*3*NN + i00;
      float sA = 0.f;
      #pragma unroll
      for (int mt=0; mt<4; mt++){
        const int hrow = (sh*64 + mt*16 + col)*HSTRB + quad*8;
        frag_ab a0 = *(const frag_ab*)&hidB[hrow];
        frag_ab a1 = *(const frag_ab*)&hidB[hrow + 32];
        frag_cd acc = {0.f,0.f,0.f,0.f};
        acc = __builtin_amdgcn_mfma_f32_16x16x32_bf16(a0, b0, acc, 0,0,0);
        acc = __builtin_amdgcn_mfma_f32_16x16x32_bf16(a1, b1, acc, 0,0,0);
        float4 vx4 = *(const float4*)&fb[mt*16];
        float4 vy4 = *(const float4*)&fb[NN + mt*16];
        float4 vz4 = *(const float4*)&fb[2*NN + mt*16];
        float4 hx4 = *(const float4*)&vhx[i00 + mt*16];
        float4 hy4 = *(const float4*)&vhy[i00 + mt*16];
        float4 hz4 = *(const float4*)&vhz[i00 + mt*16];
        float d0 = vx4.x*hx4.x + vy4.x*hy4.x + vz4.x*hz4.x;
        float d1 = vx4.y*hx4.y + vy4.y*hy4.y + vz4.y*hz4.y;
        float d2 = vx4.z*hx4.z + vy4.z*hy4.z + vz4.z*hz4.z;
        float d3 = vx4.w*hx4.w + vy4.w*hy4.w + vz4.w*hz4.w;
        sA += acc[0]*d0 + acc[1]*d1 + acc[2]*d2 + acc[3]*d3;
      }
      sA += __shfl_xor(sA, 16, 64);
      sA += __shfl_xor(sA, 32, 64);
      if (lane < 16) aggP[sh][ntg*16 + lane] = sA;
    } else if (ntg < 16){
      // m1a: tb = H * t[i,f]; 3 components via vhat
      const int f = c - (FS+FV);
      const float* fb = tIb + f*NN + i00;
      float sX=0.f, sY=0.f, sZ=0.f;
      #pragma unroll
      for (int mt=0; mt<4; mt++){
        const int hrow = (sh*64 + mt*16 + col)*HSTRB + quad*8;
        frag_ab a0 = *(const frag_ab*)&hidB[hrow];
        frag_ab a1 = *(const frag_ab*)&hidB[hrow + 32];
        frag_cd acc = {0.f,0.f,0.f,0.f};
        acc = __builtin_amdgcn_mfma_f32_16x16x32_bf16(a0, b0, acc, 0,0,0);
        acc = __builtin_amdgcn_mfma_f32_16x16x32_bf16(a1, b1, acc, 0,0,0);
        float4 t4 = *(const float4*)&fb[mt*16];
        float4 hx4 = *(const float4*)&vhx[i00 + mt*16];
        float4 hy4 = *(const float4*)&vhy[i00 + mt*16];
        float4 hz4 = *(const float4*)&vhz[i00 + mt*16];
        float t0_ = acc[0]*t4.x, t1_ = acc[1]*t4.y, t2_ = acc[2]*t4.z, t3_ = acc[3]*t4.w;
        sX += t0_*hx4.x + t1_*hx4.y + t2_*hx4.z + t3_*hx4.w;
        sY += t0_*hy4.x + t1_*hy4.y + t2_*hy4.z + t3_*hy4.w;
        sZ += t0_*hz4.x + t1_*hz4.y + t2_*hz4.z + t3_*hz4.w;
      }
      sX += __shfl_xor(sX,16,64); sX += __shfl_xor(sX,32,64);
      sY += __shfl_xor(sY,16,64); sY += __shfl_xor(sY,32,64);
      sZ += __shfl_xor(sZ,16,64); sZ += __shfl_xor(sZ,32,64);
      if (lane < 16){
        const int f2 = (ntg*16 + lane) - 192;
        aggP[sh][192 + f2*3+0]=sX; aggP[sh][192 + f2*3+1]=sY; aggP[sh][192 + f2*3+2]=sZ;
      }
    } else {
      // m1b: fac = V[i,f,c3]
      const int f = c - (FS+2*FV);
      const float* fb = vIb + f*3*NN + i00;
      float sX=0.f, sY=0.f, sZ=0.f;
      #pragma unroll
      for (int mt=0; mt<4; mt++){
        const int hrow = (sh*64 + mt*16 + col)*HSTRB + quad*8;
        frag_ab a0 = *(const frag_ab*)&hidB[hrow];
        frag_ab a1 = *(const frag_ab*)&hidB[hrow + 32];
        frag_cd acc = {0.f,0.f,0.f,0.f};
        acc = __builtin_amdgcn_mfma_f32_16x16x32_bf16(a0, b0, acc, 0,0,0);
        acc = __builtin_amdgcn_mfma_f32_16x16x32_bf16(a1, b1, acc, 0,0,0);
        float4 vx4 = *(const float4*)&fb[mt*16];
        float4 vy4 = *(const float4*)&fb[NN + mt*16];
        float4 vz4 = *(const float4*)&fb[2*NN + mt*16];
        sX += acc[0]*vx4.x + acc[1]*vx4.y + acc[2]*vx4.z + acc[3]*vx4.w;
        sY += acc[0]*vy4.x + acc[1]*vy4.y + acc[2]*vy4.z + acc[3]*vy4.w;
        sZ += acc[0]*vz4.x + acc[1]*vz4.y + acc[2]*vz4.z + acc[3]*vz4.w;
      }
      sX += __shfl_xor(sX,16,64); sX += __shfl_xor(sX,32,64);
      sY += __shfl_xor(sY,16,64); sY += __shfl_xor(sY,32,64);
      sZ += __shfl_xor(sZ,16,64); sZ += __shfl_xor(sZ,32,64);
      if (lane < 16){
        const int f2 = (ntg*16 + lane) - 256;
        aggP[sh][384 + f2*3+0]=sX; aggP[sh][384 + f2*3+1]=sY; aggP[sh][384 + f2*3+2]=sZ;
      }
    }
  }

  __syncthreads();
  for (int t2=tid; t2<576; t2+=512) aggC[t2] = (aggP[0][t2]+aggP[1][t2]) * (1.0f/128.0f);
  __syncthreads();

  const bool doOut = (WoutS != nullptr);

  // ---- epilogue: s update ----
  if (tid < FS){
    float sk = sIb[tid*NN + k];
    float a0=0.f, a1=0.f, a2=0.f, a3=0.f;
    #pragma unroll 8
    for (int cc=0; cc<192; cc+=4){
      a0 = fmaf(aggC[cc],   WmixSl[cc*FS+tid],     a0);
      a1 = fmaf(aggC[cc+1], WmixSl[(cc+1)*FS+tid], a1);
      a2 = fmaf(aggC[cc+2], WmixSl[(cc+2)*FS+tid], a2);
      a3 = fmaf(aggC[cc+3], WmixSl[(cc+3)*FS+tid], a3);
    }
    float sn = sk + silu_f((a0+a1)+(a2+a3));
    sNew[tid] = sn;
    if (!doOut) sOut[(b*FS+tid)*NN + k] = sn;
  }
  // ---- epilogue: V update ----
  if (tid < 192){
    const int g = tid/3, c3 = tid - g*3;
    float a0=0.f, a1=0.f, a2=0.f, a3=0.f;
    #pragma unroll 8
    for (int f=0; f<FV; f+=2){
      a0 = fmaf(aggC[192 + f*3+c3],     WmixVl[f*FV+g],        a0);
      a1 = fmaf(aggC[384 + f*3+c3],     WmixVl[(f+FV)*FV+g],   a1);
      a2 = fmaf(aggC[192 + (f+1)*3+c3], WmixVl[(f+1)*FV+g],    a2);
      a3 = fmaf(aggC[384 + (f+1)*3+c3], WmixVl[(f+1+FV)*FV+g], a3);
    }
    float vn = vIb[tid*NN + k] + (a0+a1)+(a2+a3);
    vNewL[tid] = vn;
    if (!doOut) vOut[(b*FV*3 + tid)*NN + k] = vn;
  }
  __syncthreads();

  if (doOut){
    // ---- fused final output: out_v then out_s (flat concat) ----
    if (tid < FS){
      float a0=0.f, a1=0.f, a2=0.f, a3=0.f;
      #pragma unroll 8
      for (int f=0; f<FS; f+=4){
        a0 = fmaf(sNew[f],   WoutS[f*FS+tid],     a0);
        a1 = fmaf(sNew[f+1], WoutS[(f+1)*FS+tid], a1);
        a2 = fmaf(sNew[f+2], WoutS[(f+2)*FS+tid], a2);
        a3 = fmaf(sNew[f+3], WoutS[(f+3)*FS+tid], a3);
      }
      outp[BATCH*NN*FV*3 + (b*NN+k)*FS + tid] = (a0+a1)+(a2+a3);
    }
    if (tid < 192){
      const int g = tid/3, c3 = tid - g*3;
      float a = comv[b*3+c3];
      #pragma unroll 8
      for (int f=0; f<FV; f++) a = fmaf(vNewL[f*3+c3], WoutV[f*FV+g], a);
      outp[(b*NN+k)*FV*3 + tid] = a;
    }
  } else if (tOut != nullptr && tid < FV){
    float a0=0.f, a1=0.f, a2=0.f, a3=0.f;
    #pragma unroll 8
    for (int f=0; f<FS; f+=4){
      a0 = fmaf(sNew[f],   WsvNext[f*FV+tid],     a0);
      a1 = fmaf(sNew[f+1], WsvNext[(f+1)*FV+tid], a1);
      a2 = fmaf(sNew[f+2], WsvNext[(f+2)*FV+tid], a2);
      a3 = fmaf(sNew[f+3], WsvNext[(f+3)*FV+tid], a3);
    }
    tOut[(b*FV+tid)*NN + k] = (a0+a1)+(a2+a3);
  }
}

extern "C" void kernel_launch(void* const* d_in, const int* in_sizes, int n_in,
                              void* d_out, int out_size, void* d_ws, size_t ws_size,
                              hipStream_t stream)
{
  const float* x       = (const float*)d_in[0];
  const float* species = (const float*)d_in[1];
  const float* Wr1     = (const float*)d_in[2];
  const float* Wr2     = (const float*)d_in[3];
  const float* Wsv     = (const float*)d_in[4];
  const float* WmixS   = (const float*)d_in[5];
  const float* WmixV   = (const float*)d_in[6];
  const float* WoutS   = (const float*)d_in[7];
  const float* WoutV   = (const float*)d_in[8];
  float* ws  = (float*)d_ws;
  float* out = (float*)d_out;

  float* sA  = ws + OFF_SA;
  float* sB  = ws + OFF_SB;
  float* vA  = ws + OFF_VA;
  float* vB  = ws + OFF_VB;
  float* t0  = ws + OFF_T0;
  float* t1  = ws + OFF_T1;
  float* com = ws + OFF_COM;
  u16*   w2b = (u16*)(ws + OFF_W2B);

  const int initTotal = SZ_S + SZ_V + SZ_T + N_W2B + 24;
  init_kernel<<<(initTotal+255)/256, 256, 0, stream>>>(x, species, Wr2, Wsv, ws);

  // layer 0: reads sA/vA/t0, writes sB/vB and t1 (t for layer 1 from updated s)
  layer_kernel<<<BATCH*NN, 512, 0, stream>>>(x, sA, vA, t0, sB, vB, t1,
      Wr1,          w2b,            WmixS,          WmixV,          Wsv + FS*FV,
      nullptr, nullptr, nullptr, nullptr);
  // layer 1: reads sB/vB/t1, fused final output to d_out
  layer_kernel<<<BATCH*NN, 512, 0, stream>>>(x, sB, vB, t1, nullptr, nullptr, nullptr,
      Wr1 + NB*HID, w2b + ROUT*HID, WmixS + 192*FS, WmixV + 128*FV, nullptr,
      WoutS, WoutV, com, out);
}

// Round 9
// 175.728 us; speedup vs baseline: 3.9740x; 1.1707x over previous
//
#include <hip/hip_runtime.h>
#include <math.h>

typedef unsigned short u16;
typedef __attribute__((ext_vector_type(8))) short frag_ab;  // 8 bf16
typedef __attribute__((ext_vector_type(4))) float frag_cd;  // 4 fp32

#define BATCH 8
#define NN 128
#define FS 128
#define FV 64
#define NB 8
#define HID 64
#define ROUT 320
#define HSTRB 72    // hid bf16 LDS row stride (shorts), layer-1 kernel
#define HSTRF 68    // hid fp32 LDS row stride (floats), layer-0 kernel

// ---- ws layout (float offsets); s:[b][f][n], V:[b][f*3+c3][n], t:[b][g][n] ----
#define SZ_S (BATCH*FS*NN)
#define SZ_V (BATCH*FV*3*NN)
#define SZ_T (BATCH*FV*NN)
#define N_W2B (ROUT*HID)            // ushort count (layer-1 only)
#define OFF_SB 0
#define OFF_VB (OFF_SB+SZ_S)
#define OFF_T1 (OFF_VB+SZ_V)
#define OFF_COM (OFF_T1+SZ_T)       // 24 floats
#define OFF_T0G (OFF_COM+24)        // 64 floats
#define OFF_W2B (OFF_T0G+64)        // N_W2B ushorts = 10240 floats

__device__ __forceinline__ float silu_f(float x){ return x * (1.0f/(1.0f + __expf(-x))); }

__device__ __forceinline__ u16 f2bf(float x){
  union { float f; unsigned int u; } v; v.f = x;
  unsigned int r = v.u + 0x7fffu + ((v.u >> 16) & 1u);
  return (u16)(r >> 16);
}

// init: w2b = bf16(Wr2[layer1]) c-major; t0g = species@Wsv0; com = mean(pos)
__global__ void init_kernel(const float* __restrict__ x, const float* __restrict__ species,
                            const float* __restrict__ Wr2, const float* __restrict__ Wsv0,
                            float* __restrict__ ws)
{
  int idx = blockIdx.x*blockDim.x + threadIdx.x;
  const int total = N_W2B + 64 + 24;
  for (; idx < total; idx += gridDim.x*blockDim.x) {
    int t = idx;
    if (t < N_W2B) {
      // w2b[c*64+j] = bf16(Wr2[1][j][c])
      int j = t & 63; int c = t>>6;
      ((u16*)(ws+OFF_W2B))[t] = f2bf(Wr2[HID*ROUT + j*ROUT + c]); continue;
    }
    t -= N_W2B;
    if (t < 64) {
      float a = 0.f;
      for (int c=0; c<FS; c++) a = fmaf(species[c], Wsv0[c*FV+t], a);
      ws[OFF_T0G+t] = a; continue;
    }
    t -= 64;
    { int bb=t/3, c3=t-bb*3;
      float a=0.f;
      for(int n=0;n<NN;n++) a += x[(bb*NN+n)*3+c3];
      ws[OFF_COM+t] = a*(1.0f/128.0f); }
  }
}

// Layer 0 specialized: s=species (uniform), V=0, t=t0g (uniform).
// agg0a[c]    = species[c]/128 * sum_j colsum0[j]*Wr2[j,c]
// agg1a[f,c3] = t0g[f]/128    * sum_j colsum_{c3}[j]*Wr2[j,192+f]
// m0b = m1b = 0. One block per (b,k); 320 threads.
__global__ __launch_bounds__(320) void layer0_kernel(
    const float* __restrict__ pos,
    const float* __restrict__ species,  // (128)
    const float* __restrict__ Wr1l,     // (8,64) layer0
    const float* __restrict__ Wr2l,     // (64,320) layer0 fp32
    const float* __restrict__ t0g,      // (64)
    const float* __restrict__ WmixSl,   // (192,128) layer0
    const float* __restrict__ WmixVl,   // (128,64) layer0
    const float* __restrict__ WsvNext,  // (128,64) layer1
    float* __restrict__ sOut,           // [b][f][n]
    float* __restrict__ vOut,           // [b][f*3+c3][n]
    float* __restrict__ tOut)           // [b][g][n]
{
  const int tid = threadIdx.x;
  const int b   = blockIdx.x >> 7;
  const int k   = blockIdx.x & 127;

  __shared__ float hidF[128*HSTRF];    // 34.8 KB
  __shared__ float vhx[128], vhy[128], vhz[128];
  __shared__ float colsum[4][64];
  __shared__ float aggS[128];
  __shared__ float aggV1[192];
  __shared__ float sNew[FS];

  const float* pb = pos + b*NN*3;

  // ---- phase 0: threads 0..255: i=t&127, half=t>>7 computes half a hid row (fp32) ----
  if (tid < 256){
    const int i    = tid & 127;
    const int half = tid >> 7;
    float vx = pb[k*3+0]-pb[i*3+0];
    float vy = pb[k*3+1]-pb[i*3+1];
    float vz = pb[k*3+2]-pb[i*3+2];
    float r = sqrtf(vx*vx+vy*vy+vz*vz) + 1e-8f;
    float inv = 1.0f/r;
    if (half==0){ vhx[i]=vx*inv; vhy[i]=vy*inv; vhz[i]=vz*inv; }
    float u = r*0.2f;
    float env = 0.0f;
    if (u < 1.0f && i != k){
      float u2=u*u, u6=u2*u2*u2;
      env = 1.0f - 28.0f*u6 + 48.0f*u6*u - 21.0f*u6*u2;
    }
    float coef = 0.6324555320336759f * inv * env;
    float arg  = r * 0.6283185307179586f;
    float rb[NB];
    #pragma unroll
    for(int n=0;n<NB;n++) rb[n] = coef * __sinf(arg*(float)(n+1));
    #pragma unroll
    for(int jg=0;jg<8;jg++){
      const int jgg = half*8 + jg;
      float h0=0.f,h1=0.f,h2=0.f,h3=0.f;
      #pragma unroll
      for(int n=0;n<NB;n++){
        const float* wr = Wr1l + n*HID + jgg*4;
        float rn = rb[n];
        h0 = fmaf(rn, wr[0], h0);
        h1 = fmaf(rn, wr[1], h1);
        h2 = fmaf(rn, wr[2], h2);
        h3 = fmaf(rn, wr[3], h3);
      }
      float4 hh = make_float4(silu_f(h0), silu_f(h1), silu_f(h2), silu_f(h3));
      *(float4*)&hidF[i*HSTRF + jgg*4] = hh;
    }
  }
  __syncthreads();

  // ---- phase A: weighted column sums over i (threads 0..255: j=t&63, var=t>>6) ----
  if (tid < 256){
    const int j   = tid & 63;
    const int var = tid >> 6;
    float acc = 0.f;
    if (var == 0){
      #pragma unroll 8
      for (int i=0;i<128;i++) acc += hidF[i*HSTRF + j];
    } else {
      const float* wv = (var==1) ? vhx : (var==2) ? vhy : vhz;
      #pragma unroll 8
      for (int i=0;i<128;i++) acc = fmaf(hidF[i*HSTRF + j], wv[i], acc);
    }
    colsum[var][j] = acc;
  }
  __syncthreads();

  // ---- phase B: project colsums through W2 columns ----
  if (tid < 128){
    const int c = tid;
    float d = 0.f;
    #pragma unroll 8
    for (int j=0;j<HID;j++) d = fmaf(colsum[0][j], Wr2l[j*ROUT + c], d);
    aggS[c] = species[c] * d * (1.0f/128.0f);
  } else {
    const int idx = tid - 128;          // 0..191
    const int f = idx & 63, c3 = idx >> 6;
    float d = 0.f;
    #pragma unroll 8
    for (int j=0;j<HID;j++) d = fmaf(colsum[1+c3][j], Wr2l[j*ROUT + 192 + f], d);
    aggV1[f*3+c3] = t0g[f] * d * (1.0f/128.0f);
  }
  __syncthreads();

  // ---- epilogue: s update (only first 128 agg channels nonzero) ----
  if (tid < FS){
    float a0=0.f, a1=0.f, a2=0.f, a3=0.f;
    #pragma unroll 8
    for (int cc=0; cc<128; cc+=4){
      a0 = fmaf(aggS[cc],   WmixSl[cc*FS+tid],     a0);
      a1 = fmaf(aggS[cc+1], WmixSl[(cc+1)*FS+tid], a1);
      a2 = fmaf(aggS[cc+2], WmixSl[(cc+2)*FS+tid], a2);
      a3 = fmaf(aggS[cc+3], WmixSl[(cc+3)*FS+tid], a3);
    }
    float sn = species[tid] + silu_f((a0+a1)+(a2+a3));
    sNew[tid] = sn;
    sOut[(b*FS+tid)*NN + k] = sn;
  }
  // ---- epilogue: V update (V_in = 0; only first 64 agg1 rows nonzero) ----
  if (tid < 192){
    const int g = tid/3, c3 = tid - g*3;
    float a0=0.f, a1=0.f;
    #pragma unroll 8
    for (int f=0; f<FV; f+=2){
      a0 = fmaf(aggV1[f*3+c3],     WmixVl[f*FV+g],     a0);
      a1 = fmaf(aggV1[(f+1)*3+c3], WmixVl[(f+1)*FV+g], a1);
    }
    vOut[(b*FV*3 + tid)*NN + k] = a0 + a1;
  }
  __syncthreads();
  // ---- t for layer 1 (from updated s) ----
  if (tid < FV){
    float a0=0.f, a1=0.f, a2=0.f, a3=0.f;
    #pragma unroll 8
    for (int f=0; f<FS; f+=4){
      a0 = fmaf(sNew[f],   WsvNext[f*FV+tid],     a0);
      a1 = fmaf(sNew[f+1], WsvNext[(f+1)*FV+tid], a1);
      a2 = fmaf(sNew[f+2], WsvNext[(f+2)*FV+tid], a2);
      a3 = fmaf(sNew[f+3], WsvNext[(f+3)*FV+tid], a3);
    }
    tOut[(b*FV+tid)*NN + k] = (a0+a1)+(a2+a3);
  }
}

// Layer-1 kernel (proven R8 body): one block per (b,k); 512 threads = 8 waves.
// wave w: wq=w&3 channel group (tiles ntg=q*4+wq), sh=w>>2 sender half.
__global__ __launch_bounds__(512) void layer_kernel(
    const float* __restrict__ pos,
    const float* __restrict__ sIn,    // [b][f][n]
    const float* __restrict__ vIn,    // [b][f*3+c3][n]
    const float* __restrict__ tIn,    // [b][g][n]
    const float* __restrict__ Wr1l,   // (8,64)
    const u16*   __restrict__ w2bl,   // (320,64) bf16, c-major
    const float* __restrict__ WmixSl, // (192,128)
    const float* __restrict__ WmixVl, // (128,64)
    const float* __restrict__ WoutS,
    const float* __restrict__ WoutV,
    const float* __restrict__ comv,
    float* __restrict__ outp)
{
  const int tid  = threadIdx.x;
  const int b    = blockIdx.x >> 7;
  const int k    = blockIdx.x & 127;
  const int w    = tid >> 6;
  const int lane = tid & 63;
  const int col  = lane & 15;
  const int quad = lane >> 4;
  const int wq   = w & 3;       // channel group
  const int sh   = w >> 2;      // sender half

  __shared__ u16   hidB[128*HSTRB];           // 18.4 KB
  __shared__ float vhx[128], vhy[128], vhz[128];
  __shared__ float aggP[2][576];
  __shared__ float aggC[576];
  __shared__ float sNew[FS];
  __shared__ float vNewL[192];

  const float* pb = pos + b*NN*3;

  if (tid < 256){
    const int i    = tid & 127;
    const int half = tid >> 7;
    float vx = pb[k*3+0]-pb[i*3+0];
    float vy = pb[k*3+1]-pb[i*3+1];
    float vz = pb[k*3+2]-pb[i*3+2];
    float r = sqrtf(vx*vx+vy*vy+vz*vz) + 1e-8f;
    float inv = 1.0f/r;
    if (half==0){ vhx[i]=vx*inv; vhy[i]=vy*inv; vhz[i]=vz*inv; }
    float u = r*0.2f;
    float env = 0.0f;
    if (u < 1.0f && i != k){
      float u2=u*u, u6=u2*u2*u2;
      env = 1.0f - 28.0f*u6 + 48.0f*u6*u - 21.0f*u6*u2;
    }
    float coef = 0.6324555320336759f * inv * env;
    float arg  = r * 0.6283185307179586f;
    float rb[NB];
    #pragma unroll
    for(int n=0;n<NB;n++) rb[n] = coef * __sinf(arg*(float)(n+1));
    u16* hrow = hidB + i*HSTRB;
    #pragma unroll
    for(int jg=0;jg<8;jg++){
      const int jgg = half*8 + jg;
      float h0=0.f,h1=0.f,h2=0.f,h3=0.f;
      #pragma unroll
      for(int n=0;n<NB;n++){
        const float* wr = Wr1l + n*HID + jgg*4;
        float rn = rb[n];
        h0 = fmaf(rn, wr[0], h0);
        h1 = fmaf(rn, wr[1], h1);
        h2 = fmaf(rn, wr[2], h2);
        h3 = fmaf(rn, wr[3], h3);
      }
      ushort4 uu = make_ushort4(f2bf(silu_f(h0)), f2bf(silu_f(h1)),
                                f2bf(silu_f(h2)), f2bf(silu_f(h3)));
      *(ushort4*)(hrow + jgg*4) = uu;
    }
  }
  __syncthreads();

  const float* sIb = sIn + b*FS*NN;
  const float* vIb = vIn + b*FV*3*NN;
  const float* tIb = tIn + b*FV*NN;
  const int i00 = sh*64 + quad*4;

  for (int q=0; q<5; q++){
    const int ntg = q*4 + wq;
    const int c   = ntg*16 + col;
    const u16* wp = w2bl + c*HID + quad*8;
    const frag_ab b0 = *(const frag_ab*)(wp);
    const frag_ab b1 = *(const frag_ab*)(wp + 32);

    if (ntg < 8){
      const float* fb = sIb + c*NN + i00;
      float sA = 0.f;
      #pragma unroll
      for (int mt=0; mt<4; mt++){
        const int hrow = (sh*64 + mt*16 + col)*HSTRB + quad*8;
        frag_ab a0 = *(const frag_ab*)&hidB[hrow];
        frag_ab a1 = *(const frag_ab*)&hidB[hrow + 32];
        frag_cd acc = {0.f,0.f,0.f,0.f};
        acc = __builtin_amdgcn_mfma_f32_16x16x32_bf16(a0, b0, acc, 0,0,0);
        acc = __builtin_amdgcn_mfma_f32_16x16x32_bf16(a1, b1, acc, 0,0,0);
        float4 s4 = *(const float4*)&fb[mt*16];
        sA += acc[0]*s4.x + acc[1]*s4.y + acc[2]*s4.z + acc[3]*s4.w;
      }
      sA += __shfl_xor(sA, 16, 64);
      sA += __shfl_xor(sA, 32, 64);
      if (lane < 16) aggP[sh][ntg*16 + lane] = sA;
    } else if (ntg < 12){
      const int f = c - FS;
      const float* fb = vIb + f*3*NN + i00;
      float sA = 0.f;
      #pragma unroll
      for (int mt=0; mt<4; mt++){
        const int hrow = (sh*64 + mt*16 + col)*HSTRB + quad*8;
        frag_ab a0 = *(const frag_ab*)&hidB[hrow];
        frag_ab a1 = *(const frag_ab*)&hidB[hrow + 32];
        frag_cd acc = {0.f,0.f,0.f,0.f};
        acc = __builtin_amdgcn_mfma_f32_16x16x32_bf16(a0, b0, acc, 0,0,0);
        acc = __builtin_amdgcn_mfma_f32_16x16x32_bf16(a1, b1, acc, 0,0,0);
        float4 vx4 = *(const float4*)&fb[mt*16];
        float4 vy4 = *(const float4*)&fb[NN + mt*16];
        float4 vz4 = *(const float4*)&fb[2*NN + mt*16];
        float4 hx4 = *(const float4*)&vhx[i00 + mt*16];
        float4 hy4 = *(const float4*)&vhy[i00 + mt*16];
        float4 hz4 = *(const float4*)&vhz[i00 + mt*16];
        float d0 = vx4.x*hx4.x + vy4.x*hy4.x + vz4.x*hz4.x;
        float d1 = vx4.y*hx4.y + vy4.y*hy4.y + vz4.y*hz4.y;
        float d2 = vx4.z*hx4.z + vy4.z*hy4.z + vz4.z*hz4.z;
        float d3 = vx4.w*hx4.w + vy4.w*hy4.w + vz4.w*hz4.w;
        sA += acc[0]*d0 + acc[1]*d1 + acc[2]*d2 + acc[3]*d3;
      }
      sA += __shfl_xor(sA, 16, 64);
      sA += __shfl_xor(sA, 32, 64);
      if (lane < 16) aggP[sh][ntg*16 + lane] = sA;
    } else if (ntg < 16){
      const int f = c - (FS+FV);
      const float* fb = tIb + f*NN + i00;
      float sX=0.f, sY=0.f, sZ=0.f;
      #pragma unroll
      for (int mt=0; mt<4; mt++){
        const int hrow = (sh*64 + mt*16 + col)*HSTRB + quad*8;
        frag_ab a0 = *(const frag_ab*)&hidB[hrow];
        frag_ab a1 = *(const frag_ab*)&hidB[hrow + 32];
        frag_cd acc = {0.f,0.f,0.f,0.f};
        acc = __builtin_amdgcn_mfma_f32_16x16x32_bf16(a0, b0, acc, 0,0,0);
        acc = __builtin_amdgcn_mfma_f32_16x16x32_bf16(a1, b1, acc, 0,0,0);
        float4 t4 = *(const float4*)&fb[mt*16];
        float4 hx4 = *(const float4*)&vhx[i00 + mt*16];
        float4 hy4 = *(const float4*)&vhy[i00 + mt*16];
        float4 hz4 = *(const float4*)&vhz[i00 + mt*16];
        float t0_ = acc[0]*t4.x, t1_ = acc[1]*t4.y, t2_ = acc[2]*t4.z, t3_ = acc[3]*t4.w;
        sX += t0_*hx4.x + t1_*hx4.y + t2_*hx4.z + t3_*hx4.w;
        sY += t0_*hy4.x + t1_*hy4.y + t2_*hy4.z + t3_*hy4.w;
        sZ += t0_*hz4.x + t1_*hz4.y + t2_*hz4.z + t3_*hz4.w;
      }
      sX += __shfl_xor(sX,16,64); sX += __shfl_xor(sX,32,64);
      sY += __shfl_xor(sY,16,64); sY += __shfl_xor(sY,32,64);
      sZ += __shfl_xor(sZ,16,64); sZ += __shfl_xor(sZ,32,64);
      if (lane < 16){
        const int f2 = (ntg*16 + lane) - 192;
        aggP[sh][192 + f2*3+0]=sX; aggP[sh][192 + f2*3+1]=sY; aggP[sh][192 + f2*3+2]=sZ;
      }
    } else {
      const int f = c - (FS+2*FV);
      const float* fb = vIb + f*3*NN + i00;
      float sX=0.f, sY=0.f, sZ=0.f;
      #pragma unroll
      for (int mt=0; mt<4; mt++){
        const int hrow = (sh*64 + mt*16 + col)*HSTRB + quad*8;
        frag_ab a0 = *(const frag_ab*)&hidB[hrow];
        frag_ab a1 = *(const frag_ab*)&hidB[hrow + 32];
        frag_cd acc = {0.f,0.f,0.f,0.f};
        acc = __builtin_amdgcn_mfma_f32_16x16x32_bf16(a0, b0, acc, 0,0,0);
        acc = __builtin_amdgcn_mfma_f32_16x16x32_bf16(a1, b1, acc, 0,0,0);
        float4 vx4 = *(const float4*)&fb[mt*16];
        float4 vy4 = *(const float4*)&fb[NN + mt*16];
        float4 vz4 = *(const float4*)&fb[2*NN + mt*16];
        sX += acc[0]*vx4.x + acc[1]*vx4.y + acc[2]*vx4.z + acc[3]*vx4.w;
        sY += acc[0]*vy4.x + acc[1]*vy4.y + acc[2]*vy4.z + acc[3]*vy4.w;
        sZ += acc[0]*vz4.x + acc[1]*vz4.y + acc[2]*vz4.z + acc[3]*vz4.w;
      }
      sX += __shfl_xor(sX,16,64); sX += __shfl_xor(sX,32,64);
      sY += __shfl_xor(sY,16,64); sY += __shfl_xor(sY,32,64);
      sZ += __shfl_xor(sZ,16,64); sZ += __shfl_xor(sZ,32,64);
      if (lane < 16){
        const int f2 = (ntg*16 + lane) - 256;
        aggP[sh][384 + f2*3+0]=sX; aggP[sh][384 + f2*3+1]=sY; aggP[sh][384 + f2*3+2]=sZ;
      }
    }
  }

  __syncthreads();
  for (int t2=tid; t2<576; t2+=512) aggC[t2] = (aggP[0][t2]+aggP[1][t2]) * (1.0f/128.0f);
  __syncthreads();

  // ---- epilogue: s / V updates ----
  if (tid < FS){
    float sk = sIb[tid*NN + k];
    float a0=0.f, a1=0.f, a2=0.f, a3=0.f;
    #pragma unroll 8
    for (int cc=0; cc<192; cc+=4){
      a0 = fmaf(aggC[cc],   WmixSl[cc*FS+tid],     a0);
      a1 = fmaf(aggC[cc+1], WmixSl[(cc+1)*FS+tid], a1);
      a2 = fmaf(aggC[cc+2], WmixSl[(cc+2)*FS+tid], a2);
      a3 = fmaf(aggC[cc+3], WmixSl[(cc+3)*FS+tid], a3);
    }
    float sn = sk + silu_f((a0+a1)+(a2+a3));
    sNew[tid] = sn;
  }
  if (tid < 192){
    const int g = tid/3, c3 = tid - g*3;
    float a0=0.f, a1=0.f, a2=0.f, a3=0.f;
    #pragma unroll 8
    for (int f=0; f<FV; f+=2){
      a0 = fmaf(aggC[192 + f*3+c3],     WmixVl[f*FV+g],        a0);
      a1 = fmaf(aggC[384 + f*3+c3],     WmixVl[(f+FV)*FV+g],   a1);
      a2 = fmaf(aggC[192 + (f+1)*3+c3], WmixVl[(f+1)*FV+g],    a2);
      a3 = fmaf(aggC[384 + (f+1)*3+c3], WmixVl[(f+1+FV)*FV+g], a3);
    }
    vNewL[tid] = vIb[tid*NN + k] + (a0+a1)+(a2+a3);
  }
  __syncthreads();

  // ---- fused final output: out_v then out_s (flat concat) ----
  if (tid < FS){
    float a0=0.f, a1=0.f, a2=0.f, a3=0.f;
    #pragma unroll 8
    for (int f=0; f<FS; f+=4){
      a0 = fmaf(sNew[f],   WoutS[f*FS+tid],     a0);
      a1 = fmaf(sNew[f+1], WoutS[(f+1)*FS+tid], a1);
      a2 = fmaf(sNew[f+2], WoutS[(f+2)*FS+tid], a2);
      a3 = fmaf(sNew[f+3], WoutS[(f+3)*FS+tid], a3);
    }
    outp[BATCH*NN*FV*3 + (b*NN+k)*FS + tid] = (a0+a1)+(a2+a3);
  }
  if (tid < 192){
    const int g = tid/3, c3 = tid - g*3;
    float a = comv[b*3+c3];
    #pragma unroll 8
    for (int f=0; f<FV; f++) a = fmaf(vNewL[f*3+c3], WoutV[f*FV+g], a);
    outp[(b*NN+k)*FV*3 + tid] = a;
  }
}

extern "C" void kernel_launch(void* const* d_in, const int* in_sizes, int n_in,
                              void* d_out, int out_size, void* d_ws, size_t ws_size,
                              hipStream_t stream)
{
  const float* x       = (const float*)d_in[0];
  const float* species = (const float*)d_in[1];
  const float* Wr1     = (const float*)d_in[2];
  const float* Wr2     = (const float*)d_in[3];
  const float* Wsv     = (const float*)d_in[4];
  const float* WmixS   = (const float*)d_in[5];
  const float* WmixV   = (const float*)d_in[6];
  const float* WoutS   = (const float*)d_in[7];
  const float* WoutV   = (const float*)d_in[8];
  float* ws  = (float*)d_ws;
  float* out = (float*)d_out;

  float* sB  = ws + OFF_SB;
  float* vB  = ws + OFF_VB;
  float* t1  = ws + OFF_T1;
  float* com = ws + OFF_COM;
  float* t0g = ws + OFF_T0G;
  u16*   w2b = (u16*)(ws + OFF_W2B);

  const int initTotal = N_W2B + 64 + 24;
  init_kernel<<<(initTotal+255)/256, 256, 0, stream>>>(x, species, Wr2, Wsv, ws);

  // layer 0 (specialized: uniform s, V=0, uniform t) -> sB, vB, t1
  layer0_kernel<<<BATCH*NN, 320, 0, stream>>>(x, species, Wr1, Wr2, t0g,
      WmixS, WmixV, Wsv + FS*FV, sB, vB, t1);

  // layer 1: reads sB/vB/t1, fused final output to d_out
  layer_kernel<<<BATCH*NN, 512, 0, stream>>>(x, sB, vB, t1,
      Wr1 + NB*HID, w2b, WmixS + 192*FS, WmixV + 128*FV,
      WoutS, WoutV, com, out);
}

// Round 10
// 162.732 us; speedup vs baseline: 4.2914x; 1.0799x over previous
//
#include <hip/hip_runtime.h>
#include <math.h>

typedef unsigned short u16;
typedef __attribute__((ext_vector_type(8))) short frag_ab;  // 8 bf16
typedef __attribute__((ext_vector_type(4))) float frag_cd;  // 4 fp32

#define BATCH 8
#define NN 128
#define FS 128
#define FV 64
#define NB 8
#define HID 64
#define ROUT 320
#define HSTRB 72    // hid bf16 LDS row stride (shorts), layer-1 kernel
#define HSTRF 68    // hid fp32 LDS row stride (floats), layer-0 kernel

// ---- ws layout (float offsets); s:[b][f][n], V:[b][f*3+c3][n], t:[b][g][n] ----
#define SZ_S (BATCH*FS*NN)
#define SZ_V (BATCH*FV*3*NN)
#define SZ_T (BATCH*FV*NN)
#define N_W2B (ROUT*HID)            // ushort count (layer-1 Wr2 in bf16)
#define OFF_SB 0
#define OFF_VB (OFF_SB+SZ_S)
#define OFF_T1 (OFF_VB+SZ_V)
#define OFF_W2B (OFF_T1+SZ_T)       // N_W2B ushorts = 10240 floats

__device__ __forceinline__ float silu_f(float x){ return x * (1.0f/(1.0f + __expf(-x))); }

__device__ __forceinline__ u16 f2bf(float x){
  union { float f; unsigned int u; } v; v.f = x;
  unsigned int r = v.u + 0x7fffu + ((v.u >> 16) & 1u);
  return (u16)(r >> 16);
}

// ---------------- Layer 0 (specialized: s=species uniform, V=0, t uniform) ----------------
// One block per (b,k); 320 threads. Also: each block converts a 20-elem slice of
// Wr2[layer1] -> bf16 w2b (consumed by layer_kernel after the kernel boundary).
__global__ __launch_bounds__(320) void layer0_kernel(
    const float* __restrict__ pos,
    const float* __restrict__ species,  // (128)
    const float* __restrict__ Wr1l,     // (8,64) layer0
    const float* __restrict__ Wr2,      // (2,64,320) fp32 (both layers)
    const float* __restrict__ Wsv,      // (2,128,64)
    const float* __restrict__ WmixSl,   // (192,128) layer0
    const float* __restrict__ WmixVl,   // (128,64) layer0
    float* __restrict__ sOut,           // [b][f][n]
    float* __restrict__ vOut,           // [b][f*3+c3][n]
    float* __restrict__ tOut,           // [b][g][n]
    u16*   __restrict__ w2b)            // (320,64) bf16 c-major, layer1
{
  const int tid = threadIdx.x;
  const int b   = blockIdx.x >> 7;
  const int k   = blockIdx.x & 127;

  __shared__ float hidF[128*HSTRF];    // 34.8 KB
  __shared__ float vhx[128], vhy[128], vhz[128];
  __shared__ float colsum[4][64];
  __shared__ float aggS[128];
  __shared__ float aggV1[192];
  __shared__ float sNew[FS];
  __shared__ float t0L[64];

  const float* pb   = pos + b*NN*3;
  const float* Wr2l = Wr2;            // layer0 fp32 (64,320)

  // ---- phase 0: tid<256: i=t&127, half=t>>7 computes half a hid row (fp32) ----
  if (tid < 256){
    const int i    = tid & 127;
    const int half = tid >> 7;
    float vx = pb[k*3+0]-pb[i*3+0];
    float vy = pb[k*3+1]-pb[i*3+1];
    float vz = pb[k*3+2]-pb[i*3+2];
    float r = sqrtf(vx*vx+vy*vy+vz*vz) + 1e-8f;
    float inv = 1.0f/r;
    if (half==0){ vhx[i]=vx*inv; vhy[i]=vy*inv; vhz[i]=vz*inv; }
    float u = r*0.2f;
    float env = 0.0f;
    if (u < 1.0f && i != k){
      float u2=u*u, u6=u2*u2*u2;
      env = 1.0f - 28.0f*u6 + 48.0f*u6*u - 21.0f*u6*u2;
    }
    float coef = 0.6324555320336759f * inv * env;
    float arg  = r * 0.6283185307179586f;
    float rb[NB];
    #pragma unroll
    for(int n=0;n<NB;n++) rb[n] = coef * __sinf(arg*(float)(n+1));
    #pragma unroll
    for(int jg=0;jg<8;jg++){
      const int jgg = half*8 + jg;
      float h0=0.f,h1=0.f,h2=0.f,h3=0.f;
      #pragma unroll
      for(int n=0;n<NB;n++){
        const float* wr = Wr1l + n*HID + jgg*4;
        float rn = rb[n];
        h0 = fmaf(rn, wr[0], h0);
        h1 = fmaf(rn, wr[1], h1);
        h2 = fmaf(rn, wr[2], h2);
        h3 = fmaf(rn, wr[3], h3);
      }
      float4 hh = make_float4(silu_f(h0), silu_f(h1), silu_f(h2), silu_f(h3));
      *(float4*)&hidF[i*HSTRF + jgg*4] = hh;
    }
  } else {
    // t0L[g] = species @ Wsv0  (uniform over nodes)
    const int g = tid - 256;   // 0..63
    float a0=0.f, a1=0.f;
    #pragma unroll 8
    for (int c=0; c<FS; c+=2){
      a0 = fmaf(species[c],   Wsv[c*FV+g],     a0);
      a1 = fmaf(species[c+1], Wsv[(c+1)*FV+g], a1);
    }
    t0L[g] = a0+a1;
  }
  __syncthreads();

  // ---- phase A: weighted column sums over i (tid<256: j=t&63, var=t>>6) ----
  if (tid < 256){
    const int j   = tid & 63;
    const int var = tid >> 6;
    float a0 = 0.f, a1 = 0.f;
    if (var == 0){
      #pragma unroll 8
      for (int i=0;i<128;i+=2){ a0 += hidF[i*HSTRF + j]; a1 += hidF[(i+1)*HSTRF + j]; }
    } else {
      const float* wv = (var==1) ? vhx : (var==2) ? vhy : vhz;
      #pragma unroll 8
      for (int i=0;i<128;i+=2){
        a0 = fmaf(hidF[i*HSTRF + j],     wv[i],   a0);
        a1 = fmaf(hidF[(i+1)*HSTRF + j], wv[i+1], a1);
      }
    }
    colsum[var][j] = a0+a1;
  } else if (tid < 276){
    // convert this block's 20-element slice of Wr2[layer1] to bf16 (for layer1)
    const int t = blockIdx.x*20 + (tid-256);   // 1024*20 = 20480 = N_W2B
    const int j = t & 63, c = t >> 6;
    w2b[t] = f2bf(Wr2[HID*ROUT + j*ROUT + c]);
  }
  __syncthreads();

  // ---- phase B: project colsums through W2 columns ----
  if (tid < 128){
    const int c = tid;
    float d0 = 0.f, d1 = 0.f;
    #pragma unroll 8
    for (int j=0;j<HID;j+=2){
      d0 = fmaf(colsum[0][j],   Wr2l[j*ROUT + c],     d0);
      d1 = fmaf(colsum[0][j+1], Wr2l[(j+1)*ROUT + c], d1);
    }
    aggS[c] = species[c] * (d0+d1) * (1.0f/128.0f);
  } else {
    const int idx = tid - 128;          // 0..191
    const int f = idx & 63, c3 = idx >> 6;
    float d0 = 0.f, d1 = 0.f;
    #pragma unroll 8
    for (int j=0;j<HID;j+=2){
      d0 = fmaf(colsum[1+c3][j],   Wr2l[j*ROUT + 192 + f],     d0);
      d1 = fmaf(colsum[1+c3][j+1], Wr2l[(j+1)*ROUT + 192 + f], d1);
    }
    aggV1[f*3+c3] = t0L[f] * (d0+d1) * (1.0f/128.0f);
  }
  __syncthreads();

  // ---- E1: s update (tid<128) | V update (tid 128..319) — disjoint ranges ----
  if (tid < FS){
    float a0=0.f, a1=0.f, a2=0.f, a3=0.f;
    #pragma unroll 8
    for (int cc=0; cc<128; cc+=4){
      a0 = fmaf(aggS[cc],   WmixSl[cc*FS+tid],     a0);
      a1 = fmaf(aggS[cc+1], WmixSl[(cc+1)*FS+tid], a1);
      a2 = fmaf(aggS[cc+2], WmixSl[(cc+2)*FS+tid], a2);
      a3 = fmaf(aggS[cc+3], WmixSl[(cc+3)*FS+tid], a3);
    }
    float sn = species[tid] + silu_f((a0+a1)+(a2+a3));
    sNew[tid] = sn;
    sOut[(b*FS+tid)*NN + k] = sn;
  } else {
    const int o = tid - 128;            // 0..191
    const int g = o/3, c3 = o - g*3;
    float a0=0.f, a1=0.f;
    #pragma unroll 8
    for (int f=0; f<FV; f+=2){
      a0 = fmaf(aggV1[f*3+c3],     WmixVl[f*FV+g],     a0);
      a1 = fmaf(aggV1[(f+1)*3+c3], WmixVl[(f+1)*FV+g], a1);
    }
    vOut[(b*FV*3 + o)*NN + k] = a0 + a1;
  }
  __syncthreads();
  // ---- E2: t for layer 1 (from updated s) ----
  if (tid < FV){
    const float* Wsv1 = Wsv + FS*FV;
    float a0=0.f, a1=0.f, a2=0.f, a3=0.f;
    #pragma unroll 8
    for (int f=0; f<FS; f+=4){
      a0 = fmaf(sNew[f],   Wsv1[f*FV+tid],     a0);
      a1 = fmaf(sNew[f+1], Wsv1[(f+1)*FV+tid], a1);
      a2 = fmaf(sNew[f+2], Wsv1[(f+2)*FV+tid], a2);
      a3 = fmaf(sNew[f+3], Wsv1[(f+3)*FV+tid], a3);
    }
    tOut[(b*FV+tid)*NN + k] = (a0+a1)+(a2+a3);
  }
}

// ---------------- Layer 1 (final): one block per (b,k); 512 threads = 8 waves ----------------
// wave w: wq=w&3 channel group, sh=w>>2 sender half. Main loop fully unrolled into
// 5 compile-time sections (q=0,1:m0a; q=2:m0b; q=3:m1a; q=4:m1b).
__global__ __launch_bounds__(512) void layer_kernel(
    const float* __restrict__ pos,
    const float* __restrict__ sIn,    // [b][f][n]
    const float* __restrict__ vIn,    // [b][f*3+c3][n]
    const float* __restrict__ tIn,    // [b][g][n]
    const float* __restrict__ Wr1l,   // (8,64) layer1
    const u16*   __restrict__ w2bl,   // (320,64) bf16, c-major
    const float* __restrict__ WmixSl, // (192,128)
    const float* __restrict__ WmixVl, // (128,64)
    const float* __restrict__ WoutS,
    const float* __restrict__ WoutV,
    float* __restrict__ outp)
{
  const int tid  = threadIdx.x;
  const int b    = blockIdx.x >> 7;
  const int k    = blockIdx.x & 127;
  const int w    = tid >> 6;
  const int lane = tid & 63;
  const int col  = lane & 15;
  const int quad = lane >> 4;
  const int wq   = w & 3;       // channel group
  const int sh   = w >> 2;      // sender half

  __shared__ u16   hidB[128*HSTRB];           // 18.4 KB
  __shared__ float vhx[128], vhy[128], vhz[128];
  __shared__ float aggP[2][576];
  __shared__ float aggC[576];
  __shared__ float sPart[2][FS];
  __shared__ float sNew[FS];
  __shared__ float vNewL[192];
  __shared__ float comL[3];

  const float* pb = pos + b*NN*3;

  if (tid < 256){
    const int i    = tid & 127;
    const int half = tid >> 7;
    float vx = pb[k*3+0]-pb[i*3+0];
    float vy = pb[k*3+1]-pb[i*3+1];
    float vz = pb[k*3+2]-pb[i*3+2];
    float r = sqrtf(vx*vx+vy*vy+vz*vz) + 1e-8f;
    float inv = 1.0f/r;
    if (half==0){ vhx[i]=vx*inv; vhy[i]=vy*inv; vhz[i]=vz*inv; }
    float u = r*0.2f;
    float env = 0.0f;
    if (u < 1.0f && i != k){
      float u2=u*u, u6=u2*u2*u2;
      env = 1.0f - 28.0f*u6 + 48.0f*u6*u - 21.0f*u6*u2;
    }
    float coef = 0.6324555320336759f * inv * env;
    float arg  = r * 0.6283185307179586f;
    float rb[NB];
    #pragma unroll
    for(int n=0;n<NB;n++) rb[n] = coef * __sinf(arg*(float)(n+1));
    u16* hrow = hidB + i*HSTRB;
    #pragma unroll
    for(int jg=0;jg<8;jg++){
      const int jgg = half*8 + jg;
      float h0=0.f,h1=0.f,h2=0.f,h3=0.f;
      #pragma unroll
      for(int n=0;n<NB;n++){
        const float* wr = Wr1l + n*HID + jgg*4;
        float rn = rb[n];
        h0 = fmaf(rn, wr[0], h0);
        h1 = fmaf(rn, wr[1], h1);
        h2 = fmaf(rn, wr[2], h2);
        h3 = fmaf(rn, wr[3], h3);
      }
      ushort4 uu = make_ushort4(f2bf(silu_f(h0)), f2bf(silu_f(h1)),
                                f2bf(silu_f(h2)), f2bf(silu_f(h3)));
      *(ushort4*)(hrow + jgg*4) = uu;
    }
  } else if (tid < 259){
    // com for this batch (needed only at out_v)
    const int c3 = tid - 256;
    float a0=0.f, a1=0.f;
    for (int n=0;n<NN;n+=2){ a0 += pb[n*3+c3]; a1 += pb[(n+1)*3+c3]; }
    comL[c3] = (a0+a1) * (1.0f/128.0f);
  }
  __syncthreads();

  const float* sIb = sIn + b*FS*NN;
  const float* vIb = vIn + b*FV*3*NN;
  const float* tIb = tIn + b*FV*NN;
  const int i00 = sh*64 + quad*4;

  // ---- section macro bodies (compile-time kind per q) ----
#define MFMA_PAIR(accv, MT) \
    { const int hrow_ = (sh*64 + (MT)*16 + col)*HSTRB + quad*8; \
      frag_ab a0_ = *(const frag_ab*)&hidB[hrow_]; \
      frag_ab a1_ = *(const frag_ab*)&hidB[hrow_ + 32]; \
      accv = __builtin_amdgcn_mfma_f32_16x16x32_bf16(a0_, b0, accv, 0,0,0); \
      accv = __builtin_amdgcn_mfma_f32_16x16x32_bf16(a1_, b1, accv, 0,0,0); }

  // q = 0,1 : m0a
  #pragma unroll
  for (int q=0; q<2; q++){
    const int ntg = q*4 + wq;
    const int c   = ntg*16 + col;
    const u16* wp = w2bl + c*HID + quad*8;
    const frag_ab b0 = *(const frag_ab*)(wp);
    const frag_ab b1 = *(const frag_ab*)(wp + 32);
    const float* fb = sIb + c*NN + i00;
    float sA = 0.f;
    #pragma unroll
    for (int mt=0; mt<4; mt++){
      frag_cd acc = {0.f,0.f,0.f,0.f};
      MFMA_PAIR(acc, mt);
      float4 s4 = *(const float4*)&fb[mt*16];
      sA += acc[0]*s4.x + acc[1]*s4.y + acc[2]*s4.z + acc[3]*s4.w;
    }
    sA += __shfl_xor(sA, 16, 64);
    sA += __shfl_xor(sA, 32, 64);
    if (lane < 16) aggP[sh][ntg*16 + lane] = sA;
  }
  // q = 2 : m0b
  {
    const int ntg = 8 + wq;
    const int c   = ntg*16 + col;
    const u16* wp = w2bl + c*HID + quad*8;
    const frag_ab b0 = *(const frag_ab*)(wp);
    const frag_ab b1 = *(const frag_ab*)(wp + 32);
    const int f = c - FS;
    const float* fb = vIb + f*3*NN + i00;
    float sA = 0.f;
    #pragma unroll
    for (int mt=0; mt<4; mt++){
      frag_cd acc = {0.f,0.f,0.f,0.f};
      MFMA_PAIR(acc, mt);
      float4 vx4 = *(const float4*)&fb[mt*16];
      float4 vy4 = *(const float4*)&fb[NN + mt*16];
      float4 vz4 = *(const float4*)&fb[2*NN + mt*16];
      float4 hx4 = *(const float4*)&vhx[i00 + mt*16];
      float4 hy4 = *(const float4*)&vhy[i00 + mt*16];
      float4 hz4 = *(const float4*)&vhz[i00 + mt*16];
      float d0 = vx4.x*hx4.x + vy4.x*hy4.x + vz4.x*hz4.x;
      float d1 = vx4.y*hx4.y + vy4.y*hy4.y + vz4.y*hz4.y;
      float d2 = vx4.z*hx4.z + vy4.z*hy4.z + vz4.z*hz4.z;
      float d3 = vx4.w*hx4.w + vy4.w*hy4.w + vz4.w*hz4.w;
      sA += acc[0]*d0 + acc[1]*d1 + acc[2]*d2 + acc[3]*d3;
    }
    sA += __shfl_xor(sA, 16, 64);
    sA += __shfl_xor(sA, 32, 64);
    if (lane < 16) aggP[sh][ntg*16 + lane] = sA;
  }
  // q = 3 : m1a
  {
    const int ntg = 12 + wq;
    const int c   = ntg*16 + col;
    const u16* wp = w2bl + c*HID + quad*8;
    const frag_ab b0 = *(const frag_ab*)(wp);
    const frag_ab b1 = *(const frag_ab*)(wp + 32);
    const int f = c - (FS+FV);
    const float* fb = tIb + f*NN + i00;
    float sX=0.f, sY=0.f, sZ=0.f;
    #pragma unroll
    for (int mt=0; mt<4; mt++){
      frag_cd acc = {0.f,0.f,0.f,0.f};
      MFMA_PAIR(acc, mt);
      float4 t4 = *(const float4*)&fb[mt*16];
      float4 hx4 = *(const float4*)&vhx[i00 + mt*16];
      float4 hy4 = *(const float4*)&vhy[i00 + mt*16];
      float4 hz4 = *(const float4*)&vhz[i00 + mt*16];
      float t0_ = acc[0]*t4.x, t1_ = acc[1]*t4.y, t2_ = acc[2]*t4.z, t3_ = acc[3]*t4.w;
      sX += t0_*hx4.x + t1_*hx4.y + t2_*hx4.z + t3_*hx4.w;
      sY += t0_*hy4.x + t1_*hy4.y + t2_*hy4.z + t3_*hy4.w;
      sZ += t0_*hz4.x + t1_*hz4.y + t2_*hz4.z + t3_*hz4.w;
    }
    sX += __shfl_xor(sX,16,64); sX += __shfl_xor(sX,32,64);
    sY += __shfl_xor(sY,16,64); sY += __shfl_xor(sY,32,64);
    sZ += __shfl_xor(sZ,16,64); sZ += __shfl_xor(sZ,32,64);
    if (lane < 16){
      const int f2 = (ntg*16 + lane) - 192;
      aggP[sh][192 + f2*3+0]=sX; aggP[sh][192 + f2*3+1]=sY; aggP[sh][192 + f2*3+2]=sZ;
    }
  }
  // q = 4 : m1b
  {
    const int ntg = 16 + wq;
    const int c   = ntg*16 + col;
    const u16* wp = w2bl + c*HID + quad*8;
    const frag_ab b0 = *(const frag_ab*)(wp);
    const frag_ab b1 = *(const frag_ab*)(wp + 32);
    const int f = c - (FS+2*FV);
    const float* fb = vIb + f*3*NN + i00;
    float sX=0.f, sY=0.f, sZ=0.f;
    #pragma unroll
    for (int mt=0; mt<4; mt++){
      frag_cd acc = {0.f,0.f,0.f,0.f};
      MFMA_PAIR(acc, mt);
      float4 vx4 = *(const float4*)&fb[mt*16];
      float4 vy4 = *(const float4*)&fb[NN + mt*16];
      float4 vz4 = *(const float4*)&fb[2*NN + mt*16];
      sX += acc[0]*vx4.x + acc[1]*vx4.y + acc[2]*vx4.z + acc[3]*vx4.w;
      sY += acc[0]*vy4.x + acc[1]*vy4.y + acc[2]*vy4.z + acc[3]*vy4.w;
      sZ += acc[0]*vz4.x + acc[1]*vz4.y + acc[2]*vz4.z + acc[3]*vz4.w;
    }
    sX += __shfl_xor(sX,16,64); sX += __shfl_xor(sX,32,64);
    sY += __shfl_xor(sY,16,64); sY += __shfl_xor(sY,32,64);
    sZ += __shfl_xor(sZ,16,64); sZ += __shfl_xor(sZ,32,64);
    if (lane < 16){
      const int f2 = (ntg*16 + lane) - 256;
      aggP[sh][384 + f2*3+0]=sX; aggP[sh][384 + f2*3+1]=sY; aggP[sh][384 + f2*3+2]=sZ;
    }
  }
#undef MFMA_PAIR

  __syncthreads();
  for (int t2=tid; t2<576; t2+=512) aggC[t2] = (aggP[0][t2]+aggP[1][t2]) * (1.0f/128.0f);
  __syncthreads();

  // ---- E1 (disjoint): s-mix partials on tid<256; V-mix on tid 256..447 ----
  if (tid < 256){
    const int o = tid & 127, p = tid >> 7;
    const int c0 = p*96;
    float a0=0.f, a1=0.f, a2=0.f, a3=0.f;
    #pragma unroll 8
    for (int cc=c0; cc<c0+96; cc+=4){
      a0 = fmaf(aggC[cc],   WmixSl[cc*FS+o],     a0);
      a1 = fmaf(aggC[cc+1], WmixSl[(cc+1)*FS+o], a1);
      a2 = fmaf(aggC[cc+2], WmixSl[(cc+2)*FS+o], a2);
      a3 = fmaf(aggC[cc+3], WmixSl[(cc+3)*FS+o], a3);
    }
    sPart[p][o] = (a0+a1)+(a2+a3);
  } else if (tid < 448){
    const int o = tid - 256;            // 0..191
    const int g = o/3, c3 = o - g*3;
    float a0=0.f, a1=0.f, a2=0.f, a3=0.f;
    #pragma unroll 8
    for (int f=0; f<FV; f+=2){
      a0 = fmaf(aggC[192 + f*3+c3],     WmixVl[f*FV+g],        a0);
      a1 = fmaf(aggC[384 + f*3+c3],     WmixVl[(f+FV)*FV+g],   a1);
      a2 = fmaf(aggC[192 + (f+1)*3+c3], WmixVl[(f+1)*FV+g],    a2);
      a3 = fmaf(aggC[384 + (f+1)*3+c3], WmixVl[(f+1+FV)*FV+g], a3);
    }
    vNewL[o] = vIb[o*NN + k] + (a0+a1)+(a2+a3);
  }
  __syncthreads();

  // ---- E2 (disjoint): s-finalize on tid<128; out_v on tid 128..319 ----
  if (tid < FS){
    float sk = sIb[tid*NN + k];
    sNew[tid] = sk + silu_f(sPart[0][tid] + sPart[1][tid]);
  } else if (tid < 320){
    const int o = tid - 128;            // 0..191
    const int g = o/3, c3 = o - g*3;
    float a = comL[c3];
    #pragma unroll 8
    for (int f=0; f<FV; f++) a = fmaf(vNewL[f*3+c3], WoutV[f*FV+g], a);
    outp[(b*NN+k)*FV*3 + o] = a;
  }
  __syncthreads();

  // ---- E3: out_s on tid<128 ----
  if (tid < FS){
    float a0=0.f, a1=0.f, a2=0.f, a3=0.f;
    #pragma unroll 8
    for (int f=0; f<FS; f+=4){
      a0 = fmaf(sNew[f],   WoutS[f*FS+tid],     a0);
      a1 = fmaf(sNew[f+1], WoutS[(f+1)*FS+tid], a1);
      a2 = fmaf(sNew[f+2], WoutS[(f+2)*FS+tid], a2);
      a3 = fmaf(sNew[f+3], WoutS[(f+3)*FS+tid], a3);
    }
    outp[BATCH*NN*FV*3 + (b*NN+k)*FS + tid] = (a0+a1)+(a2+a3);
  }
}

extern "C" void kernel_launch(void* const* d_in, const int* in_sizes, int n_in,
                              void* d_out, int out_size, void* d_ws, size_t ws_size,
                              hipStream_t stream)
{
  const float* x       = (const float*)d_in[0];
  const float* species = (const float*)d_in[1];
  const float* Wr1     = (const float*)d_in[2];
  const float* Wr2     = (const float*)d_in[3];
  const float* Wsv     = (const float*)d_in[4];
  const float* WmixS   = (const float*)d_in[5];
  const float* WmixV   = (const float*)d_in[6];
  const float* WoutS   = (const float*)d_in[7];
  const float* WoutV   = (const float*)d_in[8];
  float* ws  = (float*)d_ws;
  float* out = (float*)d_out;

  float* sB  = ws + OFF_SB;
  float* vB  = ws + OFF_VB;
  float* t1  = ws + OFF_T1;
  u16*   w2b = (u16*)(ws + OFF_W2B);

  // layer 0 (specialized) -> sB, vB, t1; also converts Wr2[layer1] -> w2b bf16
  layer0_kernel<<<BATCH*NN, 320, 0, stream>>>(x, species, Wr1, Wr2, Wsv,
      WmixS, WmixV, sB, vB, t1, w2b);

  // layer 1 (final): reads sB/vB/t1, writes d_out directly
  layer_kernel<<<BATCH*NN, 512, 0, stream>>>(x, sB, vB, t1,
      Wr1 + NB*HID, w2b, WmixS + 192*FS, WmixV + 128*FV,
      WoutS, WoutV, out);
}